// Round 9
// baseline (949.670 us; speedup 1.0000x reference)
//
#include <hip/hip_runtime.h>

#define BATCH 2
#define SEQ 4096
#define DMODEL 2048
#define DINNER 4096
#define NHEADS 64
#define HEADDIM 64
#define DSTATE 64
#define CONVDIM 4224
#define DINPROJ 8384
#define NCHUNK 64
#define CHUNKL 64
#define MROWS (BATCH*SEQ)   // 8192

typedef __bf16 bf16_t;
typedef bf16_t bf16x8 __attribute__((ext_vector_type(8)));
typedef float f32x4 __attribute__((ext_vector_type(4)));
typedef unsigned short u16;

__device__ __forceinline__ u16 f2bf(float f) {
  unsigned int u = __float_as_uint(f);
  u += 0x7fff + ((u >> 16) & 1);
  return (u16)(u >> 16);
}
__device__ __forceinline__ float bf2f(u16 s) {
  return __uint_as_float(((unsigned int)s) << 16);
}

__device__ __forceinline__ void async_load16(const void* g, void* l) {
  __builtin_amdgcn_global_load_lds(
      (const __attribute__((address_space(1))) void*)g,
      (__attribute__((address_space(3))) void*)l, 16, 0, 0);
}

// ---------------- f32 -> bf16 convert ----------------
__global__ __launch_bounds__(256) void cvt_kernel(const float* __restrict__ in,
                                                  u16* __restrict__ out, int n4) {
  int i = blockIdx.x * 256 + threadIdx.x;
  if (i >= n4) return;
  float4 v = *(const float4*)(in + (size_t)i * 4);
  ushort4 o;
  o.x = f2bf(v.x); o.y = f2bf(v.y); o.z = f2bf(v.z); o.w = f2bf(v.w);
  *(ushort4*)(out + (size_t)i * 4) = o;
}

// ---------------- pipelined bf16 GEMM, B transposed (N x K) ----------------
// 512 thr / 8 waves, tile 256x256xBK64, 2 LDS buffers (128KB), counted vmcnt(8):
//   vmcnt(8); barrier; compute(t); barrier; stage(t+2 -> buf t&1)
// Tile t+2's loads stay in flight across tile t+1's compute (no drain stall).
// XOR-swizzled LDS (pre-swizzled global source), conflict-free (verified r6).
// XCD-L2 swizzle: XCD owns mpx=gridDim.x/8 consecutive 256-row m-tiles (4MB = L2).
// EPI 0: f32 out.  EPI 1: route z(bf16) / x-preact(bf16) / BC-preact(f32) / dt(f32)
template <int EPI>
__global__ __launch_bounds__(512, 2) void gemm_bt(const u16* __restrict__ A,
                                                  const u16* __restrict__ B,
                                                  int M, int N, int K,
                                                  float* __restrict__ outf,
                                                  u16* __restrict__ z_out,
                                                  u16* __restrict__ xe_out,
                                                  float* __restrict__ bce_out,
                                                  float* __restrict__ dt_out) {
  __shared__ char smem[131072];  // 2 x (A 32KB + B 32KB)
  const int tid = threadIdx.x;
  const int w = tid >> 6, lane = tid & 63;
  // XCD-L2 swizzle
  const int id = blockIdx.y * gridDim.x + blockIdx.x;
  const int mpx = gridDim.x >> 3;
  const int xcd = id & 7;
  const int q = id >> 3;
  const int m0 = (xcd * mpx + (q % mpx)) * 256;
  const int n0 = (q / mpx) * 256;
  const int wr = (w >> 2) * 128, wc = (w & 3) * 64;  // wave owns 128(M) x 64(N)
  const int fr = lane & 15, fq = lane >> 4;
  const int nkt = K >> 6;

  // staging source pointers (pre-swizzled column so swizzled ds_read sees linear data)
  const u16* aptr[4];
  const u16* bptr[4];
#pragma unroll
  for (int p = 0; p < 4; ++p) {
    int d = p * 8192 + tid * 16;
    int row = d >> 7;                       // 128 B per row (64 bf16)
    int colb = (d & 127) ^ ((row & 7) << 4);
    aptr[p] = A + (size_t)(m0 + row) * K + (colb >> 1);
    int gn = n0 + row;
    if (gn > N - 1) gn = N - 1;
    bptr[p] = B + (size_t)gn * K + (colb >> 1);
  }

  auto stage_to = [&](int bi) {
    char* base = (char*)smem + bi * 65536;
#pragma unroll
    for (int p = 0; p < 4; ++p) {
      async_load16(aptr[p], base + p * 8192 + tid * 16);
      aptr[p] += 64;
    }
#pragma unroll
    for (int p = 0; p < 4; ++p) {
      async_load16(bptr[p], base + 32768 + p * 8192 + tid * 16);
      bptr[p] += 64;
    }
  };

  f32x4 acc[8][4];
#pragma unroll
  for (int i = 0; i < 8; ++i)
#pragma unroll
    for (int j = 0; j < 4; ++j) acc[i][j] = (f32x4){0.f, 0.f, 0.f, 0.f};

  // prologue: stage tiles 0,1 (16 loads in flight)
  stage_to(0);
  stage_to(1);

  for (int t = 0; t < nkt; ++t) {
    if (t + 1 < nkt) {
      asm volatile("s_waitcnt vmcnt(8)" ::: "memory");  // tile t landed; t+1 in flight
    } else {
      asm volatile("s_waitcnt vmcnt(0)" ::: "memory");
    }
    __builtin_amdgcn_s_barrier();
    const char* abase = (const char*)smem + (t & 1) * 65536;
    const char* bbase = abase + 32768;
#pragma unroll
    for (int ks = 0; ks < 2; ++ks) {
      bf16x8 af[8], bfr[4];
#pragma unroll
      for (int i = 0; i < 8; ++i) {
        int rowa = wr + i * 16 + fr;
        af[i] = *(const bf16x8*)(abase + ((rowa * 128 + ks * 64 + fq * 16) ^ ((fr & 7) << 4)));
      }
#pragma unroll
      for (int j = 0; j < 4; ++j) {
        int rowb = wc + j * 16 + fr;
        bfr[j] = *(const bf16x8*)(bbase + ((rowb * 128 + ks * 64 + fq * 16) ^ ((fr & 7) << 4)));
      }
      __builtin_amdgcn_s_setprio(1);
#pragma unroll
      for (int i = 0; i < 8; ++i)
#pragma unroll
        for (int j = 0; j < 4; ++j)
          acc[i][j] = __builtin_amdgcn_mfma_f32_16x16x32_bf16(af[i], bfr[j], acc[i][j], 0, 0, 0);
      __builtin_amdgcn_s_setprio(0);
    }
    __builtin_amdgcn_s_barrier();                       // all waves done reading buf t&1
    if (t + 2 < nkt) stage_to(t & 1);                   // overwrite just-freed buffer
  }

#pragma unroll
  for (int i = 0; i < 8; ++i) {
#pragma unroll
    for (int j = 0; j < 4; ++j) {
#pragma unroll
      for (int rr2 = 0; rr2 < 4; ++rr2) {
        int row = m0 + wr + i * 16 + fq * 4 + rr2;
        int col = n0 + wc + j * 16 + fr;
        float v = acc[i][j][rr2];
        if (EPI == 0) {
          if (col < N) outf[(size_t)row * N + col] = v;
        } else {
          if (col < DINNER) {
            z_out[(size_t)row * DINNER + col] = f2bf(v);
          } else if (col < 2 * DINNER) {
            xe_out[(size_t)row * DINNER + (col - DINNER)] = f2bf(v);
          } else if (col < DINNER + CONVDIM) {
            bce_out[(size_t)row * 128 + (col - 2 * DINNER)] = v;
          } else if (col < DINPROJ) {
            dt_out[(size_t)row * NHEADS + (col - DINNER - CONVDIM)] = v;
          }
        }
      }
    }
  }
}

// ---------------- fused dt softplus (in place) + per-chunk cumsum of dA ----------------
__global__ __launch_bounds__(64) void dt_acs_kernel(float* __restrict__ dt,
                                                    const float* __restrict__ dt_bias,
                                                    const float* __restrict__ A_log,
                                                    float* __restrict__ Acs) {
  const int bid = blockIdx.x;  // b*64+c
  const int h = threadIdx.x;
  const float bias = dt_bias[h];
  const float nA = -expf(A_log[h]);
  float run = 0.f;
  float* acs_row = Acs + ((size_t)bid * 64 + h) * 64;
  for (int s = 0; s < 64; ++s) {
    size_t g = ((size_t)bid * 64 + s) * 64 + h;
    float xv = dt[g] + bias;
    float sp = (xv > 20.f) ? xv : log1pf(expf(xv));
    dt[g] = sp;
    run += nA * sp;
    acs_row[s] = run;
  }
}

// ---------------- causal depthwise conv4 + silu, register window along L ----------------
__global__ __launch_bounds__(256) void conv_silu_kernel(const u16* __restrict__ xe,
                                                        const float* __restrict__ bce,
                                                        const float* __restrict__ conv_w,
                                                        const float* __restrict__ conv_b,
                                                        u16* __restrict__ xs,
                                                        float* __restrict__ Bf,
                                                        float* __restrict__ Cf) {
  const int ch8 = blockIdx.x * 256 + threadIdx.x;
  if (ch8 >= CONVDIM / 8) return;  // 528
  const int b = blockIdx.z;
  const int l0 = blockIdx.y * 64;
  const int ch0 = ch8 * 8;
  const bool isx = ch0 < DINNER;
  float w[8][4], cb[8];
#pragma unroll
  for (int j = 0; j < 8; ++j) {
    cb[j] = conv_b[ch0 + j];
#pragma unroll
    for (int t = 0; t < 4; ++t) w[j][t] = conv_w[(ch0 + j) * 4 + t];
  }
  float win[3][8];
#pragma unroll
  for (int t = 0; t < 3; ++t) {
    int l = l0 - 3 + t;
    if (l < 0) {
#pragma unroll
      for (int j = 0; j < 8; ++j) win[t][j] = 0.f;
    } else if (isx) {
      const u16* p = &xe[((size_t)b * SEQ + l) * DINNER + ch0];
      ushort4 a = *(const ushort4*)p, bq = *(const ushort4*)(p + 4);
      win[t][0] = bf2f(a.x); win[t][1] = bf2f(a.y); win[t][2] = bf2f(a.z); win[t][3] = bf2f(a.w);
      win[t][4] = bf2f(bq.x); win[t][5] = bf2f(bq.y); win[t][6] = bf2f(bq.z); win[t][7] = bf2f(bq.w);
    } else {
      const float* p = &bce[((size_t)b * SEQ + l) * 128 + (ch0 - DINNER)];
      float4 a = *(const float4*)p, bq = *(const float4*)(p + 4);
      win[t][0] = a.x; win[t][1] = a.y; win[t][2] = a.z; win[t][3] = a.w;
      win[t][4] = bq.x; win[t][5] = bq.y; win[t][6] = bq.z; win[t][7] = bq.w;
    }
  }
  for (int li = 0; li < 64; ++li) {
    const int l = l0 + li;
    float cur[8];
    if (isx) {
      const u16* p = &xe[((size_t)b * SEQ + l) * DINNER + ch0];
      ushort4 a = *(const ushort4*)p, bq = *(const ushort4*)(p + 4);
      cur[0] = bf2f(a.x); cur[1] = bf2f(a.y); cur[2] = bf2f(a.z); cur[3] = bf2f(a.w);
      cur[4] = bf2f(bq.x); cur[5] = bf2f(bq.y); cur[6] = bf2f(bq.z); cur[7] = bf2f(bq.w);
    } else {
      const float* p = &bce[((size_t)b * SEQ + l) * 128 + (ch0 - DINNER)];
      float4 a = *(const float4*)p, bq = *(const float4*)(p + 4);
      cur[0] = a.x; cur[1] = a.y; cur[2] = a.z; cur[3] = a.w;
      cur[4] = bq.x; cur[5] = bq.y; cur[6] = bq.z; cur[7] = bq.w;
    }
    float o[8];
#pragma unroll
    for (int j = 0; j < 8; ++j) {
      float acc = cb[j] + w[j][0] * win[0][j] + w[j][1] * win[1][j] +
                  w[j][2] * win[2][j] + w[j][3] * cur[j];
      o[j] = acc / (1.f + expf(-acc));
    }
    if (isx) {
      const int h = ch0 >> 6, p0 = ch0 & 63;
      u16* dst = &xs[(((size_t)b * NHEADS + h) * SEQ + l) * 64 + p0];
      ushort4 s0, s1;
      s0.x = f2bf(o[0]); s0.y = f2bf(o[1]); s0.z = f2bf(o[2]); s0.w = f2bf(o[3]);
      s1.x = f2bf(o[4]); s1.y = f2bf(o[5]); s1.z = f2bf(o[6]); s1.w = f2bf(o[7]);
      *(ushort4*)dst = s0;
      *(ushort4*)(dst + 4) = s1;
    } else {
      const int c0 = ch0 - DINNER;
      float* dst = (c0 < DSTATE) ? &Bf[((size_t)b * SEQ + l) * 64 + c0]
                                 : &Cf[((size_t)b * SEQ + l) * 64 + (c0 - DSTATE)];
      float4 f0 = {o[0], o[1], o[2], o[3]}, f1 = {o[4], o[5], o[6], o[7]};
      *(float4*)dst = f0;
      *(float4*)(dst + 4) = f1;
    }
#pragma unroll
    for (int j = 0; j < 8; ++j) { win[0][j] = win[1][j]; win[1][j] = win[2][j]; win[2][j] = cur[j]; }
  }
}

// ---------------- per-chunk states[p][n] = sum_s decay(s)*dt(s)*x[s,p]*B[s,n] ----------------
__global__ __launch_bounds__(256) void states_kernel(const u16* __restrict__ xs,
                                                     const float* __restrict__ Bf,
                                                     const float* __restrict__ Acs,
                                                     const float* __restrict__ dtp,
                                                     u16* __restrict__ states) {
  const int bid = blockIdx.x;  // (b*64+c)*64+h
  const int h = bid & 63, cc = (bid >> 6) & 63, b = bid >> 12;
  __shared__ float Xd[4096];
  __shared__ float Bl[4096];
  __shared__ float scale_s[64];
  const int tid = threadIdx.x;
  const float* acs = Acs + (size_t)bid * 64;
  if (tid < 64) {
    float alast = acs[63];
    scale_s[tid] = expf(alast - acs[tid]) * dtp[((size_t)b * SEQ + cc * 64 + tid) * 64 + h];
  }
  __syncthreads();
  {
    const int s = tid >> 2, q = (tid & 3) * 16;
    const float sc = scale_s[s];
    const u16* xp = &xs[(((size_t)b * NHEADS + h) * SEQ + cc * 64 + s) * 64 + q];
    const float* bp = &Bf[((size_t)b * SEQ + cc * 64 + s) * 64 + q];
#pragma unroll
    for (int k = 0; k < 4; ++k) {
      ushort4 xv = *(const ushort4*)(xp + k * 4);
      Xd[s * 64 + q + k * 4 + 0] = bf2f(xv.x) * sc;
      Xd[s * 64 + q + k * 4 + 1] = bf2f(xv.y) * sc;
      Xd[s * 64 + q + k * 4 + 2] = bf2f(xv.z) * sc;
      Xd[s * 64 + q + k * 4 + 3] = bf2f(xv.w) * sc;
      float4 bv = *(const float4*)(bp + k * 4);
      *(float4*)&Bl[s * 64 + q + k * 4] = bv;
    }
  }
  __syncthreads();
  const int p0 = (tid >> 4) * 4, n0 = (tid & 15) * 4;
  float av[4][4] = {};
  for (int s = 0; s < 64; ++s) {
    float4 xv = *(const float4*)&Xd[s * 64 + p0];
    float4 bv = *(const float4*)&Bl[s * 64 + n0];
    float xa[4] = {xv.x, xv.y, xv.z, xv.w};
    float ba[4] = {bv.x, bv.y, bv.z, bv.w};
#pragma unroll
    for (int i = 0; i < 4; ++i)
#pragma unroll
      for (int j = 0; j < 4; ++j) av[i][j] += xa[i] * ba[j];
  }
  u16* so = states + (size_t)bid * 4096;
#pragma unroll
  for (int i = 0; i < 4; ++i) {
    ushort4 o;
    o.x = f2bf(av[i][0]); o.y = f2bf(av[i][1]);
    o.z = f2bf(av[i][2]); o.w = f2bf(av[i][3]);
    *(ushort4*)&so[(p0 + i) * 64 + n0] = o;
  }
}

// ---------------- inter-chunk scan (in place, bf16 storage, f32 carry) ----------------
__global__ __launch_bounds__(256) void scan_kernel(u16* __restrict__ states,
                                                   const float* __restrict__ Acs) {
  int idx = blockIdx.x * 256 + threadIdx.x;  // 524288: (b,h,p,n)
  int n = idx & 63, p = (idx >> 6) & 63, h = (idx >> 12) & 63, b = idx >> 18;
  float prev = 0.f;
  for (int c = 0; c < 64; ++c) {
    size_t bid = (size_t)(b * 64 + c) * 64 + h;
    size_t off = bid * 4096 + p * 64 + n;
    float sv = bf2f(states[off]);
    float cd = expf(Acs[bid * 64 + 63]);
    states[off] = f2bf(prev);
    prev = cd * prev + sv;
  }
}

// ---------------- CB^T once per (b,c): head-independent (NGROUPS=1) ----------------
__global__ __launch_bounds__(256) void cbt_kernel(const float* __restrict__ Bf,
                                                  const float* __restrict__ Cf,
                                                  float* __restrict__ cbt) {
  const int bc = blockIdx.x;  // b*64+c
  __shared__ float Ct[64 * 65];
  __shared__ float Bt[64 * 65];
  const int tid = threadIdx.x;
  const size_t blbase = (size_t)(bc >> 6) * SEQ + (bc & 63) * 64;
  const int c4 = (tid & 15) * 4;
  for (int rr = tid >> 4; rr < 64; rr += 16) {
    float4 cv = *(const float4*)&Cf[(blbase + rr) * 64 + c4];
    float4 bv = *(const float4*)&Bf[(blbase + rr) * 64 + c4];
    Ct[rr * 65 + c4 + 0] = cv.x; Ct[rr * 65 + c4 + 1] = cv.y;
    Ct[rr * 65 + c4 + 2] = cv.z; Ct[rr * 65 + c4 + 3] = cv.w;
    Bt[rr * 65 + c4 + 0] = bv.x; Bt[rr * 65 + c4 + 1] = bv.y;
    Bt[rr * 65 + c4 + 2] = bv.z; Bt[rr * 65 + c4 + 3] = bv.w;
  }
  __syncthreads();
  const int l0 = (tid >> 4) * 4, s0 = (tid & 15) * 4;
  float a1[4][4] = {};
  for (int n = 0; n < 64; ++n) {
    float cv[4], bv[4];
#pragma unroll
    for (int i = 0; i < 4; ++i) { cv[i] = Ct[(l0 + i) * 65 + n]; bv[i] = Bt[(s0 + i) * 65 + n]; }
#pragma unroll
    for (int i = 0; i < 4; ++i)
#pragma unroll
      for (int j = 0; j < 4; ++j) a1[i][j] += cv[i] * bv[j];
  }
  float* dst = cbt + (size_t)bc * 4096;
#pragma unroll
  for (int i = 0; i < 4; ++i) {
    float4 o = {a1[i][0], a1[i][1], a1[i][2], a1[i][3]};
    *(float4*)&dst[(l0 + i) * 64 + s0] = o;
  }
}

// ---------------- per-chunk Y = (L*CBt)@xdt + expA*(C@prev^T) + D*x, gated, in place over z ----------------
__global__ __launch_bounds__(256) void y_kernel(const u16* __restrict__ xs,
                                                const float* __restrict__ cbt,
                                                const float* __restrict__ Cf,
                                                const float* __restrict__ Acs,
                                                const float* __restrict__ dtp,
                                                const u16* __restrict__ prev,
                                                const float* __restrict__ Dv,
                                                u16* __restrict__ zY) {
  const int bid = blockIdx.x;  // (b*64+c)*64+h
  const int h = bid & 63, cc = (bid >> 6) & 63, b = bid >> 12;
  const int bc = bid >> 6;     // b*64+c
  __shared__ float Ct[64 * 65];
  __shared__ float Tb[64 * 65];  // CBt -> Sm
  __shared__ float Tx[64 * 65];  // Xdt -> prev
  __shared__ float acsl[64];
  const int tid = threadIdx.x;
  const size_t blbase = (size_t)b * SEQ + cc * 64;
  if (tid < 64) acsl[tid] = Acs[(size_t)bid * 64 + tid];
  const int c4 = (tid & 15) * 4;
  for (int rr = tid >> 4; rr < 64; rr += 16) {
    float4 cv = *(const float4*)&Cf[(blbase + rr) * 64 + c4];
    float4 tv = *(const float4*)&cbt[(size_t)bc * 4096 + rr * 64 + c4];
    float dtv = dtp[(blbase + rr) * 64 + h];
    ushort4 xv = *(const ushort4*)&xs[(((size_t)b * NHEADS + h) * SEQ + cc * 64 + rr) * 64 + c4];
    Ct[rr * 65 + c4 + 0] = cv.x; Ct[rr * 65 + c4 + 1] = cv.y;
    Ct[rr * 65 + c4 + 2] = cv.z; Ct[rr * 65 + c4 + 3] = cv.w;
    Tb[rr * 65 + c4 + 0] = tv.x; Tb[rr * 65 + c4 + 1] = tv.y;
    Tb[rr * 65 + c4 + 2] = tv.z; Tb[rr * 65 + c4 + 3] = tv.w;
    Tx[rr * 65 + c4 + 0] = bf2f(xv.x) * dtv; Tx[rr * 65 + c4 + 1] = bf2f(xv.y) * dtv;
    Tx[rr * 65 + c4 + 2] = bf2f(xv.z) * dtv; Tx[rr * 65 + c4 + 3] = bf2f(xv.w) * dtv;
  }
  __syncthreads();
  const int l0 = (tid >> 4) * 4, s0 = (tid & 15) * 4;
#pragma unroll
  for (int i = 0; i < 4; ++i)
#pragma unroll
    for (int j = 0; j < 4; ++j) {
      int l = l0 + i, s = s0 + j;
      float v = Tb[l * 65 + s];
      Tb[l * 65 + s] = (l >= s) ? v * expf(acsl[l] - acsl[s]) : 0.f;
    }
  __syncthreads();
  const int p0 = s0;
  float ay[4][4] = {};
  for (int s = 0; s < 64; ++s) {
    float mv[4], xv[4];
#pragma unroll
    for (int i = 0; i < 4; ++i) mv[i] = Tb[(l0 + i) * 65 + s];
#pragma unroll
    for (int j = 0; j < 4; ++j) xv[j] = Tx[s * 65 + p0 + j];
#pragma unroll
    for (int i = 0; i < 4; ++i)
#pragma unroll
      for (int j = 0; j < 4; ++j) ay[i][j] += mv[i] * xv[j];
  }
  __syncthreads();  // done reading Tx (Xdt); reuse for prev
  for (int rr = tid >> 4; rr < 64; rr += 16) {
    ushort4 pv = *(const ushort4*)&prev[(size_t)bid * 4096 + rr * 64 + c4];
    Tx[rr * 65 + c4 + 0] = bf2f(pv.x); Tx[rr * 65 + c4 + 1] = bf2f(pv.y);
    Tx[rr * 65 + c4 + 2] = bf2f(pv.z); Tx[rr * 65 + c4 + 3] = bf2f(pv.w);
  }
  __syncthreads();
  float ao[4][4] = {};
  for (int n = 0; n < 64; ++n) {
    float cv[4], pv[4];
#pragma unroll
    for (int i = 0; i < 4; ++i) cv[i] = Ct[(l0 + i) * 65 + n];
#pragma unroll
    for (int j = 0; j < 4; ++j) pv[j] = Tx[(p0 + j) * 65 + n];
#pragma unroll
    for (int i = 0; i < 4; ++i)
#pragma unroll
      for (int j = 0; j < 4; ++j) ao[i][j] += cv[i] * pv[j];
  }
  const float Dh = Dv[h];
#pragma unroll
  for (int i = 0; i < 4; ++i) {
    float el = expf(acsl[l0 + i]);
#pragma unroll
    for (int j = 0; j < 4; ++j) {
      int l = l0 + i, p = p0 + j;
      float yv = ay[i][j] + el * ao[i][j] +
                 Dh * bf2f(xs[(((size_t)b * NHEADS + h) * SEQ + cc * 64 + l) * 64 + p]);
      size_t zoff = (blbase + l) * DINNER + h * 64 + p;
      float zv = bf2f(zY[zoff]);
      float g = yv * (zv / (1.f + expf(-zv)));
      zY[zoff] = f2bf(g);
    }
  }
}

// ---------------- RMSNorm of gated Y -> bf16 ----------------
__global__ __launch_bounds__(256) void rms_kernel(const u16* __restrict__ Y,
                                                  const float* __restrict__ nw,
                                                  u16* __restrict__ yf) {
  const int row = blockIdx.x, tid = threadIdx.x;
  const u16* yrow = Y + (size_t)row * DINNER;
  float g[16];
  float ss = 0.f;
#pragma unroll
  for (int i = 0; i < 4; ++i) {
    ushort4 yv = *(const ushort4*)&yrow[tid * 16 + i * 4];
    float ya[4] = {bf2f(yv.x), bf2f(yv.y), bf2f(yv.z), bf2f(yv.w)};
#pragma unroll
    for (int j = 0; j < 4; ++j) {
      g[i * 4 + j] = ya[j];
      ss += ya[j] * ya[j];
    }
  }
#pragma unroll
  for (int off = 32; off > 0; off >>= 1) ss += __shfl_down(ss, off, 64);
  __shared__ float red[4];
  if ((tid & 63) == 0) red[tid >> 6] = ss;
  __syncthreads();
  float tot = red[0] + red[1] + red[2] + red[3];
  float sc = rsqrtf(tot * (1.f / (float)DINNER) + 1e-5f);
#pragma unroll
  for (int i = 0; i < 4; ++i) {
    float4 nv = *(const float4*)&nw[tid * 16 + i * 4];
    float na[4] = {nv.x, nv.y, nv.z, nv.w};
    ushort4 o;
    o.x = f2bf(g[i * 4 + 0] * sc * na[0]);
    o.y = f2bf(g[i * 4 + 1] * sc * na[1]);
    o.z = f2bf(g[i * 4 + 2] * sc * na[2]);
    o.w = f2bf(g[i * 4 + 3] * sc * na[3]);
    *(ushort4*)&yf[(size_t)row * DINNER + tid * 16 + i * 4] = o;
  }
}

extern "C" void kernel_launch(void* const* d_in, const int* in_sizes, int n_in,
                              void* d_out, int out_size, void* d_ws, size_t ws_size,
                              hipStream_t stream) {
  const float* x = (const float*)d_in[0];
  const float* in_proj_w = (const float*)d_in[1];
  const float* conv_w = (const float*)d_in[2];
  const float* conv_b = (const float*)d_in[3];
  const float* dt_bias = (const float*)d_in[4];
  const float* A_log = (const float*)d_in[5];
  const float* Dvec = (const float*)d_in[6];
  const float* norm_w = (const float*)d_in[7];
  const float* out_proj_w = (const float*)d_in[8];

  char* ws = (char*)d_ws;
  // Region P1 [0, 67,895,296): xbf(32MB)+winbf(33MB) -> xs(64MB) -> yf(64MB)
  u16* xbf    = (u16*)(ws + 0);
  u16* winbf  = (u16*)(ws + 33554432);
  u16* xs     = (u16*)(ws + 0);           // after gemm1
  u16* yfbf   = (u16*)(ws + 0);           // after y_kernel
  // Region P2 [67,895,296, 135,004,160): z (bf16) -> gated Y in place
  u16* zY     = (u16*)(ws + 67895296);
  // Region P3 [135,004,160, 202,113,024): xE(bf16) -> states(bf16) -> woutbf
  u16* xe     = (u16*)(ws + 135004160);
  u16* statesb= (u16*)(ws + 135004160);   // after conv
  u16* woutbf = (u16*)(ws + 135004160);   // after y_kernel
  // Region P4 [202,113,024, 206,307,328): BC preact f32 (8192 x 128)
  float* bce  = (float*)(ws + 202113024);
  // Region P5 smalls
  float* dtb  = (float*)(ws + 206307328); // dt raw -> softplus in place (2MB)
  float* Acs  = (float*)(ws + 208404480); // 2MB
  float* Bfb  = (float*)(ws + 210501632); // 2MB
  float* Cfb  = (float*)(ws + 212598784); // 2MB
  float* cbt  = (float*)(ws + 214695936); // 2MB (end 216,793,088)

  // converts
  cvt_kernel<<<16384, 256, 0, stream>>>(x, xbf, 4194304);
  cvt_kernel<<<16768, 256, 0, stream>>>(in_proj_w, winbf, 4292608);

  // in_proj GEMM with routing epilogue (256x256 tiles: 32 x 33 blocks)
  gemm_bt<1><<<dim3(32, 33), 512, 0, stream>>>(xbf, winbf, MROWS, DINPROJ, DMODEL,
                                               nullptr, zY, xe, bce, dtb);

  // fused dt softplus + per-chunk cumsum
  dt_acs_kernel<<<128, 64, 0, stream>>>(dtb, dt_bias, A_log, Acs);

  // depthwise conv + silu (xs overwrites xbf/winbf region)
  conv_silu_kernel<<<dim3(3, 64, 2), 256, 0, stream>>>(xe, bce, conv_w, conv_b, xs, Bfb, Cfb);

  // chunked SSM (states overwrites xe region)
  states_kernel<<<8192, 256, 0, stream>>>(xs, Bfb, Acs, dtb, statesb);
  scan_kernel<<<2048, 256, 0, stream>>>(statesb, Acs);
  cbt_kernel<<<128, 256, 0, stream>>>(Bfb, Cfb, cbt);
  y_kernel<<<8192, 256, 0, stream>>>(xs, cbt, Cfb, Acs, dtb, statesb, Dvec, zY);

  // RMSNorm (yf overwrites xs region)
  rms_kernel<<<8192, 256, 0, stream>>>(zY, norm_w, yfbf);

  // out_proj weight convert (into dead states region) + out_proj GEMM
  cvt_kernel<<<8192, 256, 0, stream>>>(out_proj_w, woutbf, 2097152);
  gemm_bt<0><<<dim3(32, 8), 512, 0, stream>>>(yfbf, woutbf, MROWS, DMODEL, DINNER,
                                              (float*)d_out, nullptr, nullptr, nullptr, nullptr);
}

// Round 10
// 938.451 us; speedup vs baseline: 1.0120x; 1.0120x over previous
//
#include <hip/hip_runtime.h>

#define BATCH 2
#define SEQ 4096
#define DMODEL 2048
#define DINNER 4096
#define NHEADS 64
#define HEADDIM 64
#define DSTATE 64
#define CONVDIM 4224
#define DINPROJ 8384
#define NCHUNK 64
#define CHUNKL 64
#define MROWS (BATCH*SEQ)   // 8192

typedef __bf16 bf16_t;
typedef bf16_t bf16x8 __attribute__((ext_vector_type(8)));
typedef float f32x4 __attribute__((ext_vector_type(4)));
typedef unsigned short u16;

__device__ __forceinline__ u16 f2bf(float f) {
  unsigned int u = __float_as_uint(f);
  u += 0x7fff + ((u >> 16) & 1);
  return (u16)(u >> 16);
}
__device__ __forceinline__ float bf2f(u16 s) {
  return __uint_as_float(((unsigned int)s) << 16);
}

__device__ __forceinline__ void async_load16(const void* g, void* l) {
  __builtin_amdgcn_global_load_lds(
      (const __attribute__((address_space(1))) void*)g,
      (__attribute__((address_space(3))) void*)l, 16, 0, 0);
}

// ---------------- f32 -> bf16 convert ----------------
__global__ __launch_bounds__(256) void cvt_kernel(const float* __restrict__ in,
                                                  u16* __restrict__ out, int n4) {
  int i = blockIdx.x * 256 + threadIdx.x;
  if (i >= n4) return;
  float4 v = *(const float4*)(in + (size_t)i * 4);
  ushort4 o;
  o.x = f2bf(v.x); o.y = f2bf(v.y); o.z = f2bf(v.z); o.w = f2bf(v.w);
  *(ushort4*)(out + (size_t)i * 4) = o;
}

// ---------------- 8-phase pipelined bf16 GEMM (m201-style), B transposed (N x K) ----
// 512 thr / 8 waves (2M x 4N), tile 256x256xBK64, wave output 128x64.
// LDS 128KB = 2 dbuf x (A 2 halves 16KB + B 2 halves 16KB).
// Per K-tile: 4 phases {ds_read subtile; 1 half-stage; barrier; lgkmcnt(0)+sched_barrier;
// setprio(1); 16 MFMA; setprio(0); barrier}.  A halves read in phases (0,1)/(2,3); B in
// phase 0 only -> half-deadness allows staging tile t+2 into the SAME dbuf:
//   ph0: T(t+1).Ah1 -> other buf | ph1: T(t+2).Bh0 | ph2: T(t+2).Bh1 | ph3: T(t+2).Ah0
// End-of-tile vmcnt(6) (= 3 half-stages in flight) guarantees T(t+1) fully landed.
// XOR swizzle (row&7)<<4 on 128B rows, pre-swizzled global source (0 conflicts, r6).
// XCD-L2 swizzle: XCD owns mpx = gridDim.x/8 consecutive 256-row m-tiles.
// EPI 0: f32 out.  EPI 1: route z(bf16) / x-preact(bf16) / BC-preact(f32) / dt(f32)
template <int EPI>
__global__ __launch_bounds__(512, 2) void gemm_bt(const u16* __restrict__ A,
                                                  const u16* __restrict__ B,
                                                  int M, int N, int K,
                                                  float* __restrict__ outf,
                                                  u16* __restrict__ z_out,
                                                  u16* __restrict__ xe_out,
                                                  float* __restrict__ bce_out,
                                                  float* __restrict__ dt_out) {
  __shared__ char smem[131072];
  const int tid = threadIdx.x;
  const int w = tid >> 6, lane = tid & 63;
  const int id = blockIdx.y * gridDim.x + blockIdx.x;
  const int mpx = gridDim.x >> 3;
  const int xcd = id & 7;
  const int bq = id >> 3;
  const int m0 = (xcd * mpx + (bq % mpx)) * 256;
  const int n0 = (bq / mpx) * 256;
  const int wm = w >> 2, wn = w & 3;
  const int fr = lane & 15, fq = lane >> 4;
  const int nkt = K >> 6;

  // staging source pointers: per shot s (covers LDS bytes s*8192 + tid*16 within a half)
  const u16* aptr[2];
  const u16* bptr[2][2];  // [half][shot]
#pragma unroll
  for (int s = 0; s < 2; ++s) {
    int d = s * 8192 + tid * 16;
    int row = d >> 7;                          // row within half (128B rows)
    int colb = (d & 127) ^ ((row & 7) << 4);   // pre-swizzled source column
    aptr[s] = A + (size_t)(m0 + row) * K + (colb >> 1);
#pragma unroll
    for (int h = 0; h < 2; ++h) {
      int gn = n0 + h * 128 + row;
      if (gn > N - 1) gn = N - 1;
      bptr[h][s] = B + (size_t)gn * K + (colb >> 1);
    }
  }

  auto stageA = [&](int h, int t, int db) {
    char* dst = (char*)smem + db * 65536 + h * 16384;
#pragma unroll
    for (int s = 0; s < 2; ++s)
      async_load16(aptr[s] + (size_t)h * 128 * K + t * 64, dst + s * 8192 + tid * 16);
  };
  auto stageB = [&](int h, int t, int db) {
    char* dst = (char*)smem + db * 65536 + 32768 + h * 16384;
#pragma unroll
    for (int s = 0; s < 2; ++s)
      async_load16(bptr[h][s] + (size_t)t * 64, dst + s * 8192 + tid * 16);
  };

  f32x4 acc[4][2][4];
#pragma unroll
  for (int qq = 0; qq < 4; ++qq)
#pragma unroll
    for (int i = 0; i < 2; ++i)
#pragma unroll
      for (int j = 0; j < 4; ++j) acc[qq][i][j] = (f32x4){0.f, 0.f, 0.f, 0.f};

  bf16x8 bfr[2][4];  // [ks][j], held across the tile

  auto loadA = [&](const char* abase, int half, int r0, bf16x8 af[2][2]) {
#pragma unroll
    for (int i = 0; i < 2; ++i)
#pragma unroll
      for (int ks = 0; ks < 2; ++ks) {
        int r = r0 + i * 16 + fr;
        af[i][ks] = *(const bf16x8*)(abase + half * 16384 +
                        ((r * 128 + ks * 64 + fq * 16) ^ ((fr & 7) << 4)));
      }
  };

  // prologue: T0 all 4 halves (dbuf0), T1 Bh0,Bh1,Ah0 (dbuf1)
  stageB(0, 0, 0); stageB(1, 0, 0); stageA(0, 0, 0); stageA(1, 0, 0);
  stageB(0, 1, 1); stageB(1, 1, 1); stageA(0, 1, 1);
  asm volatile("s_waitcnt vmcnt(6)" ::: "memory");   // T0 landed
  __builtin_amdgcn_s_barrier();

  for (int t = 0; t < nkt; ++t) {
    const int d = t & 1, nd = d ^ 1;
    const char* abase = (const char*)smem + d * 65536;
    const char* bb = abase + 32768 + (wn >> 1) * 16384;
    bf16x8 af[2][2];
    // ---- phase 0: B frags (8) + A quadrant 0 (half0) ----
    {
      const int rb0 = (wn & 1) * 64;
#pragma unroll
      for (int ks = 0; ks < 2; ++ks)
#pragma unroll
        for (int j = 0; j < 4; ++j) {
          int r = rb0 + j * 16 + fr;
          bfr[ks][j] = *(const bf16x8*)(bb + ((r * 128 + ks * 64 + fq * 16) ^ ((fr & 7) << 4)));
        }
    }
    loadA(abase, 0, wm * 64, af);
    if (t + 1 < nkt) stageA(1, t + 1, nd);
    __builtin_amdgcn_s_barrier();
    asm volatile("s_waitcnt lgkmcnt(0)" ::: "memory");
    __builtin_amdgcn_sched_barrier(0);
    __builtin_amdgcn_s_setprio(1);
#pragma unroll
    for (int ks = 0; ks < 2; ++ks)
#pragma unroll
      for (int i = 0; i < 2; ++i)
#pragma unroll
        for (int j = 0; j < 4; ++j)
          acc[0][i][j] = __builtin_amdgcn_mfma_f32_16x16x32_bf16(af[i][ks], bfr[ks][j], acc[0][i][j], 0, 0, 0);
    __builtin_amdgcn_s_setprio(0);
    __builtin_amdgcn_s_barrier();
    // ---- phase 1: A quadrant 1 (half0, +32) ----
    loadA(abase, 0, wm * 64 + 32, af);
    if (t + 2 < nkt) stageB(0, t + 2, d);
    __builtin_amdgcn_s_barrier();
    asm volatile("s_waitcnt lgkmcnt(0)" ::: "memory");
    __builtin_amdgcn_sched_barrier(0);
    __builtin_amdgcn_s_setprio(1);
#pragma unroll
    for (int ks = 0; ks < 2; ++ks)
#pragma unroll
      for (int i = 0; i < 2; ++i)
#pragma unroll
        for (int j = 0; j < 4; ++j)
          acc[1][i][j] = __builtin_amdgcn_mfma_f32_16x16x32_bf16(af[i][ks], bfr[ks][j], acc[1][i][j], 0, 0, 0);
    __builtin_amdgcn_s_setprio(0);
    __builtin_amdgcn_s_barrier();
    // ---- phase 2: A quadrant 2 (half1) ----
    loadA(abase, 1, wm * 64, af);
    if (t + 2 < nkt) stageB(1, t + 2, d);
    __builtin_amdgcn_s_barrier();
    asm volatile("s_waitcnt lgkmcnt(0)" ::: "memory");
    __builtin_amdgcn_sched_barrier(0);
    __builtin_amdgcn_s_setprio(1);
#pragma unroll
    for (int ks = 0; ks < 2; ++ks)
#pragma unroll
      for (int i = 0; i < 2; ++i)
#pragma unroll
        for (int j = 0; j < 4; ++j)
          acc[2][i][j] = __builtin_amdgcn_mfma_f32_16x16x32_bf16(af[i][ks], bfr[ks][j], acc[2][i][j], 0, 0, 0);
    __builtin_amdgcn_s_setprio(0);
    __builtin_amdgcn_s_barrier();
    // ---- phase 3: A quadrant 3 (half1, +32) ----
    loadA(abase, 1, wm * 64 + 32, af);
    if (t + 2 < nkt) stageA(0, t + 2, d);
    __builtin_amdgcn_s_barrier();
    asm volatile("s_waitcnt lgkmcnt(0)" ::: "memory");
    __builtin_amdgcn_sched_barrier(0);
    __builtin_amdgcn_s_setprio(1);
#pragma unroll
    for (int ks = 0; ks < 2; ++ks)
#pragma unroll
      for (int i = 0; i < 2; ++i)
#pragma unroll
        for (int j = 0; j < 4; ++j)
          acc[3][i][j] = __builtin_amdgcn_mfma_f32_16x16x32_bf16(af[i][ks], bfr[ks][j], acc[3][i][j], 0, 0, 0);
    __builtin_amdgcn_s_setprio(0);
    __builtin_amdgcn_s_barrier();
    // ---- end of tile: counted wait for T(t+1) (3 half-stages in flight) ----
    if (t + 2 < nkt) {
      asm volatile("s_waitcnt vmcnt(6)" ::: "memory");
    } else if (t + 1 < nkt) {
      asm volatile("s_waitcnt vmcnt(0)" ::: "memory");
    }
  }

#pragma unroll
  for (int qq = 0; qq < 4; ++qq) {
#pragma unroll
    for (int i = 0; i < 2; ++i) {
#pragma unroll
      for (int j = 0; j < 4; ++j) {
#pragma unroll
        for (int rr2 = 0; rr2 < 4; ++rr2) {
          int row = m0 + (qq >> 1) * 128 + wm * 64 + (qq & 1) * 32 + i * 16 + fq * 4 + rr2;
          int col = n0 + wn * 64 + j * 16 + fr;
          float v = acc[qq][i][j][rr2];
          if (EPI == 0) {
            if (col < N) outf[(size_t)row * N + col] = v;
          } else {
            if (col < DINNER) {
              z_out[(size_t)row * DINNER + col] = f2bf(v);
            } else if (col < 2 * DINNER) {
              xe_out[(size_t)row * DINNER + (col - DINNER)] = f2bf(v);
            } else if (col < DINNER + CONVDIM) {
              bce_out[(size_t)row * 128 + (col - 2 * DINNER)] = v;
            } else if (col < DINPROJ) {
              dt_out[(size_t)row * NHEADS + (col - DINNER - CONVDIM)] = v;
            }
          }
        }
      }
    }
  }
}

// ---------------- fused dt softplus (in place) + per-chunk cumsum of dA ----------------
__global__ __launch_bounds__(64) void dt_acs_kernel(float* __restrict__ dt,
                                                    const float* __restrict__ dt_bias,
                                                    const float* __restrict__ A_log,
                                                    float* __restrict__ Acs) {
  const int bid = blockIdx.x;  // b*64+c
  const int h = threadIdx.x;
  const float bias = dt_bias[h];
  const float nA = -expf(A_log[h]);
  float run = 0.f;
  float* acs_row = Acs + ((size_t)bid * 64 + h) * 64;
  for (int s = 0; s < 64; ++s) {
    size_t g = ((size_t)bid * 64 + s) * 64 + h;
    float xv = dt[g] + bias;
    float sp = (xv > 20.f) ? xv : log1pf(expf(xv));
    dt[g] = sp;
    run += nA * sp;
    acs_row[s] = run;
  }
}

// ---------------- causal depthwise conv4 + silu, register window along L ----------------
__global__ __launch_bounds__(256) void conv_silu_kernel(const u16* __restrict__ xe,
                                                        const float* __restrict__ bce,
                                                        const float* __restrict__ conv_w,
                                                        const float* __restrict__ conv_b,
                                                        u16* __restrict__ xs,
                                                        float* __restrict__ Bf,
                                                        float* __restrict__ Cf) {
  const int ch8 = blockIdx.x * 256 + threadIdx.x;
  if (ch8 >= CONVDIM / 8) return;  // 528
  const int b = blockIdx.z;
  const int l0 = blockIdx.y * 64;
  const int ch0 = ch8 * 8;
  const bool isx = ch0 < DINNER;
  float w[8][4], cb[8];
#pragma unroll
  for (int j = 0; j < 8; ++j) {
    cb[j] = conv_b[ch0 + j];
#pragma unroll
    for (int t = 0; t < 4; ++t) w[j][t] = conv_w[(ch0 + j) * 4 + t];
  }
  float win[3][8];
#pragma unroll
  for (int t = 0; t < 3; ++t) {
    int l = l0 - 3 + t;
    if (l < 0) {
#pragma unroll
      for (int j = 0; j < 8; ++j) win[t][j] = 0.f;
    } else if (isx) {
      const u16* p = &xe[((size_t)b * SEQ + l) * DINNER + ch0];
      ushort4 a = *(const ushort4*)p, bq = *(const ushort4*)(p + 4);
      win[t][0] = bf2f(a.x); win[t][1] = bf2f(a.y); win[t][2] = bf2f(a.z); win[t][3] = bf2f(a.w);
      win[t][4] = bf2f(bq.x); win[t][5] = bf2f(bq.y); win[t][6] = bf2f(bq.z); win[t][7] = bf2f(bq.w);
    } else {
      const float* p = &bce[((size_t)b * SEQ + l) * 128 + (ch0 - DINNER)];
      float4 a = *(const float4*)p, bq = *(const float4*)(p + 4);
      win[t][0] = a.x; win[t][1] = a.y; win[t][2] = a.z; win[t][3] = a.w;
      win[t][4] = bq.x; win[t][5] = bq.y; win[t][6] = bq.z; win[t][7] = bq.w;
    }
  }
  for (int li = 0; li < 64; ++li) {
    const int l = l0 + li;
    float cur[8];
    if (isx) {
      const u16* p = &xe[((size_t)b * SEQ + l) * DINNER + ch0];
      ushort4 a = *(const ushort4*)p, bq = *(const ushort4*)(p + 4);
      cur[0] = bf2f(a.x); cur[1] = bf2f(a.y); cur[2] = bf2f(a.z); cur[3] = bf2f(a.w);
      cur[4] = bf2f(bq.x); cur[5] = bf2f(bq.y); cur[6] = bf2f(bq.z); cur[7] = bf2f(bq.w);
    } else {
      const float* p = &bce[((size_t)b * SEQ + l) * 128 + (ch0 - DINNER)];
      float4 a = *(const float4*)p, bq = *(const float4*)(p + 4);
      cur[0] = a.x; cur[1] = a.y; cur[2] = a.z; cur[3] = a.w;
      cur[4] = bq.x; cur[5] = bq.y; cur[6] = bq.z; cur[7] = bq.w;
    }
    float o[8];
#pragma unroll
    for (int j = 0; j < 8; ++j) {
      float acc = cb[j] + w[j][0] * win[0][j] + w[j][1] * win[1][j] +
                  w[j][2] * win[2][j] + w[j][3] * cur[j];
      o[j] = acc / (1.f + expf(-acc));
    }
    if (isx) {
      const int h = ch0 >> 6, p0 = ch0 & 63;
      u16* dst = &xs[(((size_t)b * NHEADS + h) * SEQ + l) * 64 + p0];
      ushort4 s0, s1;
      s0.x = f2bf(o[0]); s0.y = f2bf(o[1]); s0.z = f2bf(o[2]); s0.w = f2bf(o[3]);
      s1.x = f2bf(o[4]); s1.y = f2bf(o[5]); s1.z = f2bf(o[6]); s1.w = f2bf(o[7]);
      *(ushort4*)dst = s0;
      *(ushort4*)(dst + 4) = s1;
    } else {
      const int c0 = ch0 - DINNER;
      float* dst = (c0 < DSTATE) ? &Bf[((size_t)b * SEQ + l) * 64 + c0]
                                 : &Cf[((size_t)b * SEQ + l) * 64 + (c0 - DSTATE)];
      float4 f0 = {o[0], o[1], o[2], o[3]}, f1 = {o[4], o[5], o[6], o[7]};
      *(float4*)dst = f0;
      *(float4*)(dst + 4) = f1;
    }
#pragma unroll
    for (int j = 0; j < 8; ++j) { win[0][j] = win[1][j]; win[1][j] = win[2][j]; win[2][j] = cur[j]; }
  }
}

// ---------------- per-chunk states[p][n] = sum_s decay(s)*dt(s)*x[s,p]*B[s,n] ----------------
__global__ __launch_bounds__(256) void states_kernel(const u16* __restrict__ xs,
                                                     const float* __restrict__ Bf,
                                                     const float* __restrict__ Acs,
                                                     const float* __restrict__ dtp,
                                                     u16* __restrict__ states) {
  const int bid = blockIdx.x;  // (b*64+c)*64+h
  const int h = bid & 63, cc = (bid >> 6) & 63, b = bid >> 12;
  __shared__ float Xd[4096];
  __shared__ float Bl[4096];
  __shared__ float scale_s[64];
  const int tid = threadIdx.x;
  const float* acs = Acs + (size_t)bid * 64;
  if (tid < 64) {
    float alast = acs[63];
    scale_s[tid] = expf(alast - acs[tid]) * dtp[((size_t)b * SEQ + cc * 64 + tid) * 64 + h];
  }
  __syncthreads();
  {
    const int s = tid >> 2, q = (tid & 3) * 16;
    const float sc = scale_s[s];
    const u16* xp = &xs[(((size_t)b * NHEADS + h) * SEQ + cc * 64 + s) * 64 + q];
    const float* bp = &Bf[((size_t)b * SEQ + cc * 64 + s) * 64 + q];
#pragma unroll
    for (int k = 0; k < 4; ++k) {
      ushort4 xv = *(const ushort4*)(xp + k * 4);
      Xd[s * 64 + q + k * 4 + 0] = bf2f(xv.x) * sc;
      Xd[s * 64 + q + k * 4 + 1] = bf2f(xv.y) * sc;
      Xd[s * 64 + q + k * 4 + 2] = bf2f(xv.z) * sc;
      Xd[s * 64 + q + k * 4 + 3] = bf2f(xv.w) * sc;
      float4 bv = *(const float4*)(bp + k * 4);
      *(float4*)&Bl[s * 64 + q + k * 4] = bv;
    }
  }
  __syncthreads();
  const int p0 = (tid >> 4) * 4, n0 = (tid & 15) * 4;
  float av[4][4] = {};
  for (int s = 0; s < 64; ++s) {
    float4 xv = *(const float4*)&Xd[s * 64 + p0];
    float4 bv = *(const float4*)&Bl[s * 64 + n0];
    float xa[4] = {xv.x, xv.y, xv.z, xv.w};
    float ba[4] = {bv.x, bv.y, bv.z, bv.w};
#pragma unroll
    for (int i = 0; i < 4; ++i)
#pragma unroll
      for (int j = 0; j < 4; ++j) av[i][j] += xa[i] * ba[j];
  }
  u16* so = states + (size_t)bid * 4096;
#pragma unroll
  for (int i = 0; i < 4; ++i) {
    ushort4 o;
    o.x = f2bf(av[i][0]); o.y = f2bf(av[i][1]);
    o.z = f2bf(av[i][2]); o.w = f2bf(av[i][3]);
    *(ushort4*)&so[(p0 + i) * 64 + n0] = o;
  }
}

// ---------------- inter-chunk scan (in place, bf16 storage, f32 carry) ----------------
__global__ __launch_bounds__(256) void scan_kernel(u16* __restrict__ states,
                                                   const float* __restrict__ Acs) {
  int idx = blockIdx.x * 256 + threadIdx.x;  // 524288: (b,h,p,n)
  int n = idx & 63, p = (idx >> 6) & 63, h = (idx >> 12) & 63, b = idx >> 18;
  float prev = 0.f;
  for (int c = 0; c < 64; ++c) {
    size_t bid = (size_t)(b * 64 + c) * 64 + h;
    size_t off = bid * 4096 + p * 64 + n;
    float sv = bf2f(states[off]);
    float cd = expf(Acs[bid * 64 + 63]);
    states[off] = f2bf(prev);
    prev = cd * prev + sv;
  }
}

// ---------------- CB^T once per (b,c): head-independent (NGROUPS=1) ----------------
__global__ __launch_bounds__(256) void cbt_kernel(const float* __restrict__ Bf,
                                                  const float* __restrict__ Cf,
                                                  float* __restrict__ cbt) {
  const int bc = blockIdx.x;  // b*64+c
  __shared__ float Ct[64 * 65];
  __shared__ float Bt[64 * 65];
  const int tid = threadIdx.x;
  const size_t blbase = (size_t)(bc >> 6) * SEQ + (bc & 63) * 64;
  const int c4 = (tid & 15) * 4;
  for (int rr = tid >> 4; rr < 64; rr += 16) {
    float4 cv = *(const float4*)&Cf[(blbase + rr) * 64 + c4];
    float4 bv = *(const float4*)&Bf[(blbase + rr) * 64 + c4];
    Ct[rr * 65 + c4 + 0] = cv.x; Ct[rr * 65 + c4 + 1] = cv.y;
    Ct[rr * 65 + c4 + 2] = cv.z; Ct[rr * 65 + c4 + 3] = cv.w;
    Bt[rr * 65 + c4 + 0] = bv.x; Bt[rr * 65 + c4 + 1] = bv.y;
    Bt[rr * 65 + c4 + 2] = bv.z; Bt[rr * 65 + c4 + 3] = bv.w;
  }
  __syncthreads();
  const int l0 = (tid >> 4) * 4, s0 = (tid & 15) * 4;
  float a1[4][4] = {};
  for (int n = 0; n < 64; ++n) {
    float cv[4], bv[4];
#pragma unroll
    for (int i = 0; i < 4; ++i) { cv[i] = Ct[(l0 + i) * 65 + n]; bv[i] = Bt[(s0 + i) * 65 + n]; }
#pragma unroll
    for (int i = 0; i < 4; ++i)
#pragma unroll
      for (int j = 0; j < 4; ++j) a1[i][j] += cv[i] * bv[j];
  }
  float* dst = cbt + (size_t)bc * 4096;
#pragma unroll
  for (int i = 0; i < 4; ++i) {
    float4 o = {a1[i][0], a1[i][1], a1[i][2], a1[i][3]};
    *(float4*)&dst[(l0 + i) * 64 + s0] = o;
  }
}

// ---------------- per-chunk Y = (L*CBt)@xdt + expA*(C@prev^T) + D*x, gated, in place over z ----------------
__global__ __launch_bounds__(256) void y_kernel(const u16* __restrict__ xs,
                                                const float* __restrict__ cbt,
                                                const float* __restrict__ Cf,
                                                const float* __restrict__ Acs,
                                                const float* __restrict__ dtp,
                                                const u16* __restrict__ prev,
                                                const float* __restrict__ Dv,
                                                u16* __restrict__ zY) {
  const int bid = blockIdx.x;  // (b*64+c)*64+h
  const int h = bid & 63, cc = (bid >> 6) & 63, b = bid >> 12;
  const int bc = bid >> 6;     // b*64+c
  __shared__ float Ct[64 * 65];
  __shared__ float Tb[64 * 65];  // CBt -> Sm
  __shared__ float Tx[64 * 65];  // Xdt -> prev
  __shared__ float acsl[64];
  const int tid = threadIdx.x;
  const size_t blbase = (size_t)b * SEQ + cc * 64;
  if (tid < 64) acsl[tid] = Acs[(size_t)bid * 64 + tid];
  const int c4 = (tid & 15) * 4;
  for (int rr = tid >> 4; rr < 64; rr += 16) {
    float4 cv = *(const float4*)&Cf[(blbase + rr) * 64 + c4];
    float4 tv = *(const float4*)&cbt[(size_t)bc * 4096 + rr * 64 + c4];
    float dtv = dtp[(blbase + rr) * 64 + h];
    ushort4 xv = *(const ushort4*)&xs[(((size_t)b * NHEADS + h) * SEQ + cc * 64 + rr) * 64 + c4];
    Ct[rr * 65 + c4 + 0] = cv.x; Ct[rr * 65 + c4 + 1] = cv.y;
    Ct[rr * 65 + c4 + 2] = cv.z; Ct[rr * 65 + c4 + 3] = cv.w;
    Tb[rr * 65 + c4 + 0] = tv.x; Tb[rr * 65 + c4 + 1] = tv.y;
    Tb[rr * 65 + c4 + 2] = tv.z; Tb[rr * 65 + c4 + 3] = tv.w;
    Tx[rr * 65 + c4 + 0] = bf2f(xv.x) * dtv; Tx[rr * 65 + c4 + 1] = bf2f(xv.y) * dtv;
    Tx[rr * 65 + c4 + 2] = bf2f(xv.z) * dtv; Tx[rr * 65 + c4 + 3] = bf2f(xv.w) * dtv;
  }
  __syncthreads();
  const int l0 = (tid >> 4) * 4, s0 = (tid & 15) * 4;
#pragma unroll
  for (int i = 0; i < 4; ++i)
#pragma unroll
    for (int j = 0; j < 4; ++j) {
      int l = l0 + i, s = s0 + j;
      float v = Tb[l * 65 + s];
      Tb[l * 65 + s] = (l >= s) ? v * expf(acsl[l] - acsl[s]) : 0.f;
    }
  __syncthreads();
  const int p0 = s0;
  float ay[4][4] = {};
  for (int s = 0; s < 64; ++s) {
    float mv[4], xv[4];
#pragma unroll
    for (int i = 0; i < 4; ++i) mv[i] = Tb[(l0 + i) * 65 + s];
#pragma unroll
    for (int j = 0; j < 4; ++j) xv[j] = Tx[s * 65 + p0 + j];
#pragma unroll
    for (int i = 0; i < 4; ++i)
#pragma unroll
      for (int j = 0; j < 4; ++j) ay[i][j] += mv[i] * xv[j];
  }
  __syncthreads();  // done reading Tx (Xdt); reuse for prev
  for (int rr = tid >> 4; rr < 64; rr += 16) {
    ushort4 pv = *(const ushort4*)&prev[(size_t)bid * 4096 + rr * 64 + c4];
    Tx[rr * 65 + c4 + 0] = bf2f(pv.x); Tx[rr * 65 + c4 + 1] = bf2f(pv.y);
    Tx[rr * 65 + c4 + 2] = bf2f(pv.z); Tx[rr * 65 + c4 + 3] = bf2f(pv.w);
  }
  __syncthreads();
  float ao[4][4] = {};
  for (int n = 0; n < 64; ++n) {
    float cv[4], pv[4];
#pragma unroll
    for (int i = 0; i < 4; ++i) cv[i] = Ct[(l0 + i) * 65 + n];
#pragma unroll
    for (int j = 0; j < 4; ++j) pv[j] = Tx[(p0 + j) * 65 + n];
#pragma unroll
    for (int i = 0; i < 4; ++i)
#pragma unroll
      for (int j = 0; j < 4; ++j) ao[i][j] += cv[i] * pv[j];
  }
  const float Dh = Dv[h];
#pragma unroll
  for (int i = 0; i < 4; ++i) {
    float el = expf(acsl[l0 + i]);
#pragma unroll
    for (int j = 0; j < 4; ++j) {
      int l = l0 + i, p = p0 + j;
      float yv = ay[i][j] + el * ao[i][j] +
                 Dh * bf2f(xs[(((size_t)b * NHEADS + h) * SEQ + cc * 64 + l) * 64 + p]);
      size_t zoff = (blbase + l) * DINNER + h * 64 + p;
      float zv = bf2f(zY[zoff]);
      float g = yv * (zv / (1.f + expf(-zv)));
      zY[zoff] = f2bf(g);
    }
  }
}

// ---------------- RMSNorm of gated Y -> bf16 ----------------
__global__ __launch_bounds__(256) void rms_kernel(const u16* __restrict__ Y,
                                                  const float* __restrict__ nw,
                                                  u16* __restrict__ yf) {
  const int row = blockIdx.x, tid = threadIdx.x;
  const u16* yrow = Y + (size_t)row * DINNER;
  float g[16];
  float ss = 0.f;
#pragma unroll
  for (int i = 0; i < 4; ++i) {
    ushort4 yv = *(const ushort4*)&yrow[tid * 16 + i * 4];
    float ya[4] = {bf2f(yv.x), bf2f(yv.y), bf2f(yv.z), bf2f(yv.w)};
#pragma unroll
    for (int j = 0; j < 4; ++j) {
      g[i * 4 + j] = ya[j];
      ss += ya[j] * ya[j];
    }
  }
#pragma unroll
  for (int off = 32; off > 0; off >>= 1) ss += __shfl_down(ss, off, 64);
  __shared__ float red[4];
  if ((tid & 63) == 0) red[tid >> 6] = ss;
  __syncthreads();
  float tot = red[0] + red[1] + red[2] + red[3];
  float sc = rsqrtf(tot * (1.f / (float)DINNER) + 1e-5f);
#pragma unroll
  for (int i = 0; i < 4; ++i) {
    float4 nv = *(const float4*)&nw[tid * 16 + i * 4];
    float na[4] = {nv.x, nv.y, nv.z, nv.w};
    ushort4 o;
    o.x = f2bf(g[i * 4 + 0] * sc * na[0]);
    o.y = f2bf(g[i * 4 + 1] * sc * na[1]);
    o.z = f2bf(g[i * 4 + 2] * sc * na[2]);
    o.w = f2bf(g[i * 4 + 3] * sc * na[3]);
    *(ushort4*)&yf[(size_t)row * DINNER + tid * 16 + i * 4] = o;
  }
}

extern "C" void kernel_launch(void* const* d_in, const int* in_sizes, int n_in,
                              void* d_out, int out_size, void* d_ws, size_t ws_size,
                              hipStream_t stream) {
  const float* x = (const float*)d_in[0];
  const float* in_proj_w = (const float*)d_in[1];
  const float* conv_w = (const float*)d_in[2];
  const float* conv_b = (const float*)d_in[3];
  const float* dt_bias = (const float*)d_in[4];
  const float* A_log = (const float*)d_in[5];
  const float* Dvec = (const float*)d_in[6];
  const float* norm_w = (const float*)d_in[7];
  const float* out_proj_w = (const float*)d_in[8];

  char* ws = (char*)d_ws;
  // Region P1 [0, 67,895,296): xbf(32MB)+winbf(33MB) -> xs(64MB) -> yf(64MB)
  u16* xbf    = (u16*)(ws + 0);
  u16* winbf  = (u16*)(ws + 33554432);
  u16* xs     = (u16*)(ws + 0);           // after gemm1
  u16* yfbf   = (u16*)(ws + 0);           // after y_kernel
  // Region P2 [67,895,296, 135,004,160): z (bf16) -> gated Y in place
  u16* zY     = (u16*)(ws + 67895296);
  // Region P3 [135,004,160, 202,113,024): xE(bf16) -> states(bf16) -> woutbf
  u16* xe     = (u16*)(ws + 135004160);
  u16* statesb= (u16*)(ws + 135004160);   // after conv
  u16* woutbf = (u16*)(ws + 135004160);   // after y_kernel
  // Region P4 [202,113,024, 206,307,328): BC preact f32 (8192 x 128)
  float* bce  = (float*)(ws + 202113024);
  // Region P5 smalls
  float* dtb  = (float*)(ws + 206307328); // dt raw -> softplus in place (2MB)
  float* Acs  = (float*)(ws + 208404480); // 2MB
  float* Bfb  = (float*)(ws + 210501632); // 2MB
  float* Cfb  = (float*)(ws + 212598784); // 2MB
  float* cbt  = (float*)(ws + 214695936); // 2MB (end 216,793,088)

  // converts
  cvt_kernel<<<16384, 256, 0, stream>>>(x, xbf, 4194304);
  cvt_kernel<<<16768, 256, 0, stream>>>(in_proj_w, winbf, 4292608);

  // in_proj GEMM with routing epilogue (256x256 tiles: 32 x 33 blocks)
  gemm_bt<1><<<dim3(32, 33), 512, 0, stream>>>(xbf, winbf, MROWS, DINPROJ, DMODEL,
                                               nullptr, zY, xe, bce, dtb);

  // fused dt softplus + per-chunk cumsum
  dt_acs_kernel<<<128, 64, 0, stream>>>(dtb, dt_bias, A_log, Acs);

  // depthwise conv + silu (xs overwrites xbf/winbf region)
  conv_silu_kernel<<<dim3(3, 64, 2), 256, 0, stream>>>(xe, bce, conv_w, conv_b, xs, Bfb, Cfb);

  // chunked SSM (states overwrites xe region)
  states_kernel<<<8192, 256, 0, stream>>>(xs, Bfb, Acs, dtb, statesb);
  scan_kernel<<<2048, 256, 0, stream>>>(statesb, Acs);
  cbt_kernel<<<128, 256, 0, stream>>>(Bfb, Cfb, cbt);
  y_kernel<<<8192, 256, 0, stream>>>(xs, cbt, Cfb, Acs, dtb, statesb, Dvec, zY);

  // RMSNorm (yf overwrites xs region)
  rms_kernel<<<8192, 256, 0, stream>>>(zY, norm_w, yfbf);

  // out_proj weight convert (into dead states region) + out_proj GEMM
  cvt_kernel<<<8192, 256, 0, stream>>>(out_proj_w, woutbf, 2097152);
  gemm_bt<0><<<dim3(32, 8), 512, 0, stream>>>(yfbf, woutbf, MROWS, DMODEL, DINNER,
                                              (float*)d_out, nullptr, nullptr, nullptr, nullptr);
}

// Round 11
// 801.074 us; speedup vs baseline: 1.1855x; 1.1715x over previous
//
#include <hip/hip_runtime.h>

#define BATCH 2
#define SEQ 4096
#define DMODEL 2048
#define DINNER 4096
#define NHEADS 64
#define HEADDIM 64
#define DSTATE 64
#define CONVDIM 4224
#define DINPROJ 8384
#define NCHUNK 64
#define CHUNKL 64
#define MROWS (BATCH*SEQ)   // 8192

typedef __bf16 bf16_t;
typedef bf16_t bf16x8 __attribute__((ext_vector_type(8)));
typedef float f32x4 __attribute__((ext_vector_type(4)));
typedef unsigned short u16;
typedef u16 u16x8 __attribute__((ext_vector_type(8)));

__device__ __forceinline__ u16 f2bf(float f) {
  unsigned int u = __float_as_uint(f);
  u += 0x7fff + ((u >> 16) & 1);
  return (u16)(u >> 16);
}
__device__ __forceinline__ float bf2f(u16 s) {
  return __uint_as_float(((unsigned int)s) << 16);
}

__device__ __forceinline__ void async_load16(const void* g, void* l) {
  __builtin_amdgcn_global_load_lds(
      (const __attribute__((address_space(1))) void*)g,
      (__attribute__((address_space(3))) void*)l, 16, 0, 0);
}

// ---------------- f32 -> bf16 convert ----------------
__global__ __launch_bounds__(256) void cvt_kernel(const float* __restrict__ in,
                                                  u16* __restrict__ out, int n4) {
  int i = blockIdx.x * 256 + threadIdx.x;
  if (i >= n4) return;
  float4 v = *(const float4*)(in + (size_t)i * 4);
  ushort4 o;
  o.x = f2bf(v.x); o.y = f2bf(v.y); o.z = f2bf(v.z); o.w = f2bf(v.w);
  *(ushort4*)(out + (size_t)i * 4) = o;
}

// ---------------- pipelined bf16 GEMM, B transposed (N x K)  [r7 structure, best] ----
// 512 thr / 8 waves, tile 128x256xBK64, 3 LDS buffers, counted vmcnt(6),
// 1 barrier per K-tile, XOR-swizzled LDS (pre-swizzled global source).
// XCD-L2 swizzle: XCD x owns m-tiles [8x,8x+8) (A-slice = 4MB = L2).
// Requires gridDim.x == 64.
// EPI 0: f32 out.  EPI 1: route z(bf16) / x-preact(bf16) / BC-preact(f32) / dt(f32)
template <int EPI>
__global__ __launch_bounds__(512, 2) void gemm_bt(const u16* __restrict__ A,
                                                  const u16* __restrict__ B,
                                                  int M, int N, int K,
                                                  float* __restrict__ outf,
                                                  u16* __restrict__ z_out,
                                                  u16* __restrict__ xe_out,
                                                  float* __restrict__ bce_out,
                                                  float* __restrict__ dt_out) {
  __shared__ char smem[147456];  // 3 x (A 16KB + B 32KB)
  const int tid = threadIdx.x;
  const int w = tid >> 6, lane = tid & 63;
  const int id = blockIdx.y * gridDim.x + blockIdx.x;
  const int xcd = id & 7;
  const int q = id >> 3;
  const int m0 = (xcd * 8 + (q & 7)) * 128;
  const int n0 = (q >> 3) * 256;
  const int wr = (w >> 2) * 64, wc = (w & 3) * 64;
  const int fr = lane & 15, fq = lane >> 4;
  const int nkt = K >> 6;

  const u16* aptr[2];
  const u16* bptr[4];
#pragma unroll
  for (int p = 0; p < 2; ++p) {
    int d = p * 8192 + tid * 16;
    int row = d >> 7;
    int colb = (d & 127) ^ ((row & 7) << 4);
    aptr[p] = A + (size_t)(m0 + row) * K + (colb >> 1);
  }
#pragma unroll
  for (int p = 0; p < 4; ++p) {
    int d = p * 8192 + tid * 16;
    int row = d >> 7;
    int colb = (d & 127) ^ ((row & 7) << 4);
    int gn = n0 + row;
    if (gn > N - 1) gn = N - 1;
    bptr[p] = B + (size_t)gn * K + (colb >> 1);
  }

  auto stage_to = [&](int bi) {
    char* base = (char*)smem + bi * 49152;
#pragma unroll
    for (int p = 0; p < 2; ++p) {
      async_load16(aptr[p], base + p * 8192 + tid * 16);
      aptr[p] += 64;
    }
#pragma unroll
    for (int p = 0; p < 4; ++p) {
      async_load16(bptr[p], base + 16384 + p * 8192 + tid * 16);
      bptr[p] += 64;
    }
  };

  auto load_frags = [&](int bi, int ks, bf16x8* af, bf16x8* bf) {
    const char* base = (const char*)smem + bi * 49152;
#pragma unroll
    for (int i = 0; i < 4; ++i) {
      int rowa = wr + i * 16 + fr;
      af[i] = *(const bf16x8*)(base + ((rowa * 128 + ks * 64 + fq * 16) ^ ((fr & 7) << 4)));
      int rowb = wc + i * 16 + fr;
      bf[i] = *(const bf16x8*)(base + 16384 +
                               ((rowb * 128 + ks * 64 + fq * 16) ^ ((fr & 7) << 4)));
    }
  };

  f32x4 acc[4][4];
#pragma unroll
  for (int i = 0; i < 4; ++i)
#pragma unroll
    for (int j = 0; j < 4; ++j) acc[i][j] = (f32x4){0.f, 0.f, 0.f, 0.f};

  stage_to(0);
  stage_to(1);
  asm volatile("s_waitcnt vmcnt(6)" ::: "memory");
  __builtin_amdgcn_s_barrier();

  bf16x8 a0[4], b0[4], a1[4], b1[4];
  load_frags(0, 0, a0, b0);

  int cur = 0;
  for (int t = 0; t < nkt; ++t) {
    int nx = cur + 1; if (nx == 3) nx = 0;
    int st = nx + 1; if (st == 3) st = 0;
    load_frags(cur, 1, a1, b1);
    const bool do_stage = (t + 2 < nkt);
    if (do_stage) stage_to(st);
    __builtin_amdgcn_s_setprio(1);
#pragma unroll
    for (int i = 0; i < 4; ++i)
#pragma unroll
      for (int j = 0; j < 4; ++j)
        acc[i][j] = __builtin_amdgcn_mfma_f32_16x16x32_bf16(a0[i], b0[j], acc[i][j], 0, 0, 0);
    __builtin_amdgcn_s_setprio(0);
    if (do_stage) {
      asm volatile("s_waitcnt vmcnt(6)" ::: "memory");
    } else {
      asm volatile("s_waitcnt vmcnt(0)" ::: "memory");
    }
    __builtin_amdgcn_s_barrier();
    if (t + 1 < nkt) load_frags(nx, 0, a0, b0);
    __builtin_amdgcn_s_setprio(1);
#pragma unroll
    for (int i = 0; i < 4; ++i)
#pragma unroll
      for (int j = 0; j < 4; ++j)
        acc[i][j] = __builtin_amdgcn_mfma_f32_16x16x32_bf16(a1[i], b1[j], acc[i][j], 0, 0, 0);
    __builtin_amdgcn_s_setprio(0);
    cur = nx;
  }

#pragma unroll
  for (int i = 0; i < 4; ++i) {
#pragma unroll
    for (int j = 0; j < 4; ++j) {
#pragma unroll
      for (int rr2 = 0; rr2 < 4; ++rr2) {
        int row = m0 + wr + i * 16 + fq * 4 + rr2;
        int col = n0 + wc + j * 16 + fr;
        float v = acc[i][j][rr2];
        if (EPI == 0) {
          if (col < N) outf[(size_t)row * N + col] = v;
        } else {
          if (col < DINNER) {
            z_out[(size_t)row * DINNER + col] = f2bf(v);
          } else if (col < 2 * DINNER) {
            xe_out[(size_t)row * DINNER + (col - DINNER)] = f2bf(v);
          } else if (col < DINNER + CONVDIM) {
            bce_out[(size_t)row * 128 + (col - 2 * DINNER)] = v;
          } else if (col < DINPROJ) {
            dt_out[(size_t)row * NHEADS + (col - DINNER - CONVDIM)] = v;
          }
        }
      }
    }
  }
}

// ---------------- fused dt softplus (in place) + per-chunk cumsum of dA ----------------
__global__ __launch_bounds__(64) void dt_acs_kernel(float* __restrict__ dt,
                                                    const float* __restrict__ dt_bias,
                                                    const float* __restrict__ A_log,
                                                    float* __restrict__ Acs) {
  const int bid = blockIdx.x;  // b*64+c
  const int h = threadIdx.x;
  const float bias = dt_bias[h];
  const float nA = -expf(A_log[h]);
  float run = 0.f;
  float* acs_row = Acs + ((size_t)bid * 64 + h) * 64;
  for (int s = 0; s < 64; ++s) {
    size_t g = ((size_t)bid * 64 + s) * 64 + h;
    float xv = dt[g] + bias;
    float sp = (xv > 20.f) ? xv : log1pf(expf(xv));
    dt[g] = sp;
    run += nA * sp;
    acs_row[s] = run;
  }
}

// ---------------- causal depthwise conv4 + silu, register window along L ----------------
__global__ __launch_bounds__(256) void conv_silu_kernel(const u16* __restrict__ xe,
                                                        const float* __restrict__ bce,
                                                        const float* __restrict__ conv_w,
                                                        const float* __restrict__ conv_b,
                                                        u16* __restrict__ xs,
                                                        float* __restrict__ Bf,
                                                        float* __restrict__ Cf) {
  const int ch8 = blockIdx.x * 256 + threadIdx.x;
  if (ch8 >= CONVDIM / 8) return;  // 528
  const int b = blockIdx.z;
  const int l0 = blockIdx.y * 64;
  const int ch0 = ch8 * 8;
  const bool isx = ch0 < DINNER;
  float w[8][4], cb[8];
#pragma unroll
  for (int j = 0; j < 8; ++j) {
    cb[j] = conv_b[ch0 + j];
#pragma unroll
    for (int t = 0; t < 4; ++t) w[j][t] = conv_w[(ch0 + j) * 4 + t];
  }
  float win[3][8];
#pragma unroll
  for (int t = 0; t < 3; ++t) {
    int l = l0 - 3 + t;
    if (l < 0) {
#pragma unroll
      for (int j = 0; j < 8; ++j) win[t][j] = 0.f;
    } else if (isx) {
      const u16* p = &xe[((size_t)b * SEQ + l) * DINNER + ch0];
      ushort4 a = *(const ushort4*)p, bq = *(const ushort4*)(p + 4);
      win[t][0] = bf2f(a.x); win[t][1] = bf2f(a.y); win[t][2] = bf2f(a.z); win[t][3] = bf2f(a.w);
      win[t][4] = bf2f(bq.x); win[t][5] = bf2f(bq.y); win[t][6] = bf2f(bq.z); win[t][7] = bf2f(bq.w);
    } else {
      const float* p = &bce[((size_t)b * SEQ + l) * 128 + (ch0 - DINNER)];
      float4 a = *(const float4*)p, bq = *(const float4*)(p + 4);
      win[t][0] = a.x; win[t][1] = a.y; win[t][2] = a.z; win[t][3] = a.w;
      win[t][4] = bq.x; win[t][5] = bq.y; win[t][6] = bq.z; win[t][7] = bq.w;
    }
  }
  for (int li = 0; li < 64; ++li) {
    const int l = l0 + li;
    float cur[8];
    if (isx) {
      const u16* p = &xe[((size_t)b * SEQ + l) * DINNER + ch0];
      ushort4 a = *(const ushort4*)p, bq = *(const ushort4*)(p + 4);
      cur[0] = bf2f(a.x); cur[1] = bf2f(a.y); cur[2] = bf2f(a.z); cur[3] = bf2f(a.w);
      cur[4] = bf2f(bq.x); cur[5] = bf2f(bq.y); cur[6] = bf2f(bq.z); cur[7] = bf2f(bq.w);
    } else {
      const float* p = &bce[((size_t)b * SEQ + l) * 128 + (ch0 - DINNER)];
      float4 a = *(const float4*)p, bq = *(const float4*)(p + 4);
      cur[0] = a.x; cur[1] = a.y; cur[2] = a.z; cur[3] = a.w;
      cur[4] = bq.x; cur[5] = bq.y; cur[6] = bq.z; cur[7] = bq.w;
    }
    float o[8];
#pragma unroll
    for (int j = 0; j < 8; ++j) {
      float acc = cb[j] + w[j][0] * win[0][j] + w[j][1] * win[1][j] +
                  w[j][2] * win[2][j] + w[j][3] * cur[j];
      o[j] = acc / (1.f + expf(-acc));
    }
    if (isx) {
      const int h = ch0 >> 6, p0 = ch0 & 63;
      u16* dst = &xs[(((size_t)b * NHEADS + h) * SEQ + l) * 64 + p0];
      ushort4 s0, s1;
      s0.x = f2bf(o[0]); s0.y = f2bf(o[1]); s0.z = f2bf(o[2]); s0.w = f2bf(o[3]);
      s1.x = f2bf(o[4]); s1.y = f2bf(o[5]); s1.z = f2bf(o[6]); s1.w = f2bf(o[7]);
      *(ushort4*)dst = s0;
      *(ushort4*)(dst + 4) = s1;
    } else {
      const int c0 = ch0 - DINNER;
      float* dst = (c0 < DSTATE) ? &Bf[((size_t)b * SEQ + l) * 64 + c0]
                                 : &Cf[((size_t)b * SEQ + l) * 64 + (c0 - DSTATE)];
      float4 f0 = {o[0], o[1], o[2], o[3]}, f1 = {o[4], o[5], o[6], o[7]};
      *(float4*)dst = f0;
      *(float4*)(dst + 4) = f1;
    }
#pragma unroll
    for (int j = 0; j < 8; ++j) { win[0][j] = win[1][j]; win[1][j] = win[2][j]; win[2][j] = cur[j]; }
  }
}

// ---------------- per-chunk states[p][n] = sum_s decay(s)*dt(s)*x[s,p]*B[s,n] ----------------
__global__ __launch_bounds__(256) void states_kernel(const u16* __restrict__ xs,
                                                     const float* __restrict__ Bf,
                                                     const float* __restrict__ Acs,
                                                     const float* __restrict__ dtp,
                                                     u16* __restrict__ states) {
  const int bid = blockIdx.x;  // (b*64+c)*64+h
  const int h = bid & 63, cc = (bid >> 6) & 63, b = bid >> 12;
  __shared__ float Xd[4096];
  __shared__ float Bl[4096];
  __shared__ float scale_s[64];
  const int tid = threadIdx.x;
  const float* acs = Acs + (size_t)bid * 64;
  if (tid < 64) {
    float alast = acs[63];
    scale_s[tid] = expf(alast - acs[tid]) * dtp[((size_t)b * SEQ + cc * 64 + tid) * 64 + h];
  }
  __syncthreads();
  {
    const int s = tid >> 2, q = (tid & 3) * 16;
    const float sc = scale_s[s];
    const u16* xp = &xs[(((size_t)b * NHEADS + h) * SEQ + cc * 64 + s) * 64 + q];
    const float* bp = &Bf[((size_t)b * SEQ + cc * 64 + s) * 64 + q];
#pragma unroll
    for (int k = 0; k < 4; ++k) {
      ushort4 xv = *(const ushort4*)(xp + k * 4);
      Xd[s * 64 + q + k * 4 + 0] = bf2f(xv.x) * sc;
      Xd[s * 64 + q + k * 4 + 1] = bf2f(xv.y) * sc;
      Xd[s * 64 + q + k * 4 + 2] = bf2f(xv.z) * sc;
      Xd[s * 64 + q + k * 4 + 3] = bf2f(xv.w) * sc;
      float4 bv = *(const float4*)(bp + k * 4);
      *(float4*)&Bl[s * 64 + q + k * 4] = bv;
    }
  }
  __syncthreads();
  const int p0 = (tid >> 4) * 4, n0 = (tid & 15) * 4;
  float av[4][4] = {};
  for (int s = 0; s < 64; ++s) {
    float4 xv = *(const float4*)&Xd[s * 64 + p0];
    float4 bv = *(const float4*)&Bl[s * 64 + n0];
    float xa[4] = {xv.x, xv.y, xv.z, xv.w};
    float ba[4] = {bv.x, bv.y, bv.z, bv.w};
#pragma unroll
    for (int i = 0; i < 4; ++i)
#pragma unroll
      for (int j = 0; j < 4; ++j) av[i][j] += xa[i] * ba[j];
  }
  u16* so = states + (size_t)bid * 4096;
#pragma unroll
  for (int i = 0; i < 4; ++i) {
    ushort4 o;
    o.x = f2bf(av[i][0]); o.y = f2bf(av[i][1]);
    o.z = f2bf(av[i][2]); o.w = f2bf(av[i][3]);
    *(ushort4*)&so[(p0 + i) * 64 + n0] = o;
  }
}

// ---------------- inter-chunk scan (in place, bf16 storage, f32 carry) ----------------
__global__ __launch_bounds__(256) void scan_kernel(u16* __restrict__ states,
                                                   const float* __restrict__ Acs) {
  int idx = blockIdx.x * 256 + threadIdx.x;  // 524288: (b,h,p,n)
  int n = idx & 63, p = (idx >> 6) & 63, h = (idx >> 12) & 63, b = idx >> 18;
  float prev = 0.f;
  for (int c = 0; c < 64; ++c) {
    size_t bid = (size_t)(b * 64 + c) * 64 + h;
    size_t off = bid * 4096 + p * 64 + n;
    float sv = bf2f(states[off]);
    float cd = expf(Acs[bid * 64 + 63]);
    states[off] = f2bf(prev);
    prev = cd * prev + sv;
  }
}

// ---------------- CB^T once per (b,c): head-independent (NGROUPS=1) ----------------
__global__ __launch_bounds__(256) void cbt_kernel(const float* __restrict__ Bf,
                                                  const float* __restrict__ Cf,
                                                  float* __restrict__ cbt) {
  const int bc = blockIdx.x;  // b*64+c
  __shared__ float Ct[64 * 65];
  __shared__ float Bt[64 * 65];
  const int tid = threadIdx.x;
  const size_t blbase = (size_t)(bc >> 6) * SEQ + (bc & 63) * 64;
  const int c4 = (tid & 15) * 4;
  for (int rr = tid >> 4; rr < 64; rr += 16) {
    float4 cv = *(const float4*)&Cf[(blbase + rr) * 64 + c4];
    float4 bv = *(const float4*)&Bf[(blbase + rr) * 64 + c4];
    Ct[rr * 65 + c4 + 0] = cv.x; Ct[rr * 65 + c4 + 1] = cv.y;
    Ct[rr * 65 + c4 + 2] = cv.z; Ct[rr * 65 + c4 + 3] = cv.w;
    Bt[rr * 65 + c4 + 0] = bv.x; Bt[rr * 65 + c4 + 1] = bv.y;
    Bt[rr * 65 + c4 + 2] = bv.z; Bt[rr * 65 + c4 + 3] = bv.w;
  }
  __syncthreads();
  const int l0 = (tid >> 4) * 4, s0 = (tid & 15) * 4;
  float a1[4][4] = {};
  for (int n = 0; n < 64; ++n) {
    float cv[4], bv[4];
#pragma unroll
    for (int i = 0; i < 4; ++i) { cv[i] = Ct[(l0 + i) * 65 + n]; bv[i] = Bt[(s0 + i) * 65 + n]; }
#pragma unroll
    for (int i = 0; i < 4; ++i)
#pragma unroll
      for (int j = 0; j < 4; ++j) a1[i][j] += cv[i] * bv[j];
  }
  float* dst = cbt + (size_t)bc * 4096;
#pragma unroll
  for (int i = 0; i < 4; ++i) {
    float4 o = {a1[i][0], a1[i][1], a1[i][2], a1[i][3]};
    *(float4*)&dst[(l0 + i) * 64 + s0] = o;
  }
}

// ---------------- MFMA y_kernel: Y = (L*CBt)@xdt + expA*(C@prev^T) + D*x, gated ----------------
// 256 thr / 4 waves.  LDS: 4 bf16 64x64 tiles (8KB each), XOR-swizzled like gemm:
//   Cb (C), Pb (prev), Sb (Sm = tril(CBt * exp(acsl_l - acsl_s))), Xb (Xdt^T).
// Wave w owns l-strip [16w,16w+16); per wave: 2 a-frag loads x2 + 8 b-frag loads x2,
// 16 mfma_f32_16x16x32_bf16.  D layout: row l = fq*4+reg, col p = fr (gemm-verified).
__global__ __launch_bounds__(256) void y_kernel(const u16* __restrict__ xs,
                                                const float* __restrict__ cbt,
                                                const float* __restrict__ Cf,
                                                const float* __restrict__ Acs,
                                                const float* __restrict__ dtp,
                                                const u16* __restrict__ prev,
                                                const float* __restrict__ Dv,
                                                u16* __restrict__ zY) {
  const int bid = blockIdx.x;  // (b*64+c)*64+h
  const int h = bid & 63, cc = (bid >> 6) & 63, b = bid >> 12;
  const int bc = bid >> 6;
  __shared__ char lds[32768 + 256];
  char* Cb = lds;
  char* Pb = lds + 8192;
  char* Sb = lds + 16384;
  char* Xb = lds + 24576;
  float* acsl = (float*)(lds + 32768);
  const int tid = threadIdx.x;
  const size_t blbase = (size_t)b * SEQ + cc * 64;
  if (tid < 64) acsl[tid] = Acs[(size_t)bid * 64 + tid];

  const int r = tid >> 2, c0 = (tid & 3) * 16;  // each thread: row r, 16 cols at c0
  // Cb fill: C[r][c0..+15] f32 -> bf16, swizzled rows
  {
    const float* src = &Cf[(blbase + r) * 64 + c0];
    float4 a = *(const float4*)src, bq = *(const float4*)(src + 4);
    float4 c2 = *(const float4*)(src + 8), d2 = *(const float4*)(src + 12);
    u16x8 v0 = {f2bf(a.x), f2bf(a.y), f2bf(a.z), f2bf(a.w),
                f2bf(bq.x), f2bf(bq.y), f2bf(bq.z), f2bf(bq.w)};
    u16x8 v1 = {f2bf(c2.x), f2bf(c2.y), f2bf(c2.z), f2bf(c2.w),
                f2bf(d2.x), f2bf(d2.y), f2bf(d2.z), f2bf(d2.w)};
    *(u16x8*)(Cb + ((r * 128 + c0 * 2) ^ ((r & 7) << 4))) = v0;
    *(u16x8*)(Cb + ((r * 128 + c0 * 2 + 16) ^ ((r & 7) << 4))) = v1;
  }
  // Pb fill: prev[r][c0..+15] bf16 direct, swizzled
  {
    const u16* src = &prev[(size_t)bid * 4096 + r * 64 + c0];
    u16x8 v0 = *(const u16x8*)src, v1 = *(const u16x8*)(src + 8);
    *(u16x8*)(Pb + ((r * 128 + c0 * 2) ^ ((r & 7) << 4))) = v0;
    *(u16x8*)(Pb + ((r * 128 + c0 * 2 + 16) ^ ((r & 7) << 4))) = v1;
  }
  // Xb fill (transpose): Xb[p][s=r] = xs[r][p] * dt[r], p = c0..c0+15
  {
    float dtv = dtp[(blbase + r) * 64 + h];
    const u16* src = &xs[(((size_t)b * NHEADS + h) * SEQ + cc * 64 + r) * 64 + c0];
    u16x8 x0 = *(const u16x8*)src, x1 = *(const u16x8*)(src + 8);
#pragma unroll
    for (int k = 0; k < 16; ++k) {
      u16 xv = (k < 8) ? x0[k] : x1[k - 8];
      u16 o = f2bf(bf2f(xv) * dtv);
      int p = c0 + k;
      *(u16*)(Xb + ((p * 128 + r * 2) ^ ((p & 7) << 4))) = o;
    }
  }
  __syncthreads();
  // Sb fill: Sm[r][s] = (r>=s) ? cbt[r][s]*exp(acsl[r]-acsl[s]) : 0  (needs acsl)
  {
    float al = acsl[r];
    const float* src = &cbt[(size_t)bc * 4096 + r * 64 + c0];
    u16 ov[16];
#pragma unroll
    for (int k = 0; k < 16; ++k) {
      int s = c0 + k;
      float v = (r >= s) ? src[k] * expf(al - acsl[s]) : 0.f;
      ov[k] = f2bf(v);
    }
    u16x8 v0 = {ov[0], ov[1], ov[2], ov[3], ov[4], ov[5], ov[6], ov[7]};
    u16x8 v1 = {ov[8], ov[9], ov[10], ov[11], ov[12], ov[13], ov[14], ov[15]};
    *(u16x8*)(Sb + ((r * 128 + c0 * 2) ^ ((r & 7) << 4))) = v0;
    *(u16x8*)(Sb + ((r * 128 + c0 * 2 + 16) ^ ((r & 7) << 4))) = v1;
  }
  __syncthreads();

  const int w = tid >> 6, lane = tid & 63;
  const int fr = lane & 15, fq = lane >> 4;
  const int lw = w * 16;
  auto ldf = [&](const char* base, int row, int ks) -> bf16x8 {
    return *(const bf16x8*)(base + ((row * 128 + ks * 64 + fq * 16) ^ ((row & 7) << 4)));
  };
  bf16x8 aS[2], aC[2];
#pragma unroll
  for (int ks = 0; ks < 2; ++ks) {
    aS[ks] = ldf(Sb, lw + fr, ks);
    aC[ks] = ldf(Cb, lw + fr, ks);
  }
  f32x4 ay[4], ao[4];
#pragma unroll
  for (int j = 0; j < 4; ++j) { ay[j] = (f32x4){0.f,0.f,0.f,0.f}; ao[j] = (f32x4){0.f,0.f,0.f,0.f}; }
#pragma unroll
  for (int j = 0; j < 4; ++j) {
#pragma unroll
    for (int ks = 0; ks < 2; ++ks) {
      bf16x8 bX = ldf(Xb, j * 16 + fr, ks);
      ay[j] = __builtin_amdgcn_mfma_f32_16x16x32_bf16(aS[ks], bX, ay[j], 0, 0, 0);
      bf16x8 bP = ldf(Pb, j * 16 + fr, ks);
      ao[j] = __builtin_amdgcn_mfma_f32_16x16x32_bf16(aC[ks], bP, ao[j], 0, 0, 0);
    }
  }
  const float Dh = Dv[h];
  float el[4];
#pragma unroll
  for (int reg = 0; reg < 4; ++reg) el[reg] = expf(acsl[lw + fq * 4 + reg]);
#pragma unroll
  for (int j = 0; j < 4; ++j) {
#pragma unroll
    for (int reg = 0; reg < 4; ++reg) {
      int l = lw + fq * 4 + reg, p = j * 16 + fr;
      float yv = ay[j][reg] + el[reg] * ao[j][reg] +
                 Dh * bf2f(xs[(((size_t)b * NHEADS + h) * SEQ + cc * 64 + l) * 64 + p]);
      size_t zoff = (blbase + l) * DINNER + h * 64 + p;
      float zv = bf2f(zY[zoff]);
      zY[zoff] = f2bf(yv * (zv / (1.f + expf(-zv))));
    }
  }
}

// ---------------- RMSNorm of gated Y -> bf16 ----------------
__global__ __launch_bounds__(256) void rms_kernel(const u16* __restrict__ Y,
                                                  const float* __restrict__ nw,
                                                  u16* __restrict__ yf) {
  const int row = blockIdx.x, tid = threadIdx.x;
  const u16* yrow = Y + (size_t)row * DINNER;
  float g[16];
  float ss = 0.f;
#pragma unroll
  for (int i = 0; i < 4; ++i) {
    ushort4 yv = *(const ushort4*)&yrow[tid * 16 + i * 4];
    float ya[4] = {bf2f(yv.x), bf2f(yv.y), bf2f(yv.z), bf2f(yv.w)};
#pragma unroll
    for (int j = 0; j < 4; ++j) {
      g[i * 4 + j] = ya[j];
      ss += ya[j] * ya[j];
    }
  }
#pragma unroll
  for (int off = 32; off > 0; off >>= 1) ss += __shfl_down(ss, off, 64);
  __shared__ float red[4];
  if ((tid & 63) == 0) red[tid >> 6] = ss;
  __syncthreads();
  float tot = red[0] + red[1] + red[2] + red[3];
  float sc = rsqrtf(tot * (1.f / (float)DINNER) + 1e-5f);
#pragma unroll
  for (int i = 0; i < 4; ++i) {
    float4 nv = *(const float4*)&nw[tid * 16 + i * 4];
    float na[4] = {nv.x, nv.y, nv.z, nv.w};
    ushort4 o;
    o.x = f2bf(g[i * 4 + 0] * sc * na[0]);
    o.y = f2bf(g[i * 4 + 1] * sc * na[1]);
    o.z = f2bf(g[i * 4 + 2] * sc * na[2]);
    o.w = f2bf(g[i * 4 + 3] * sc * na[3]);
    *(ushort4*)&yf[(size_t)row * DINNER + tid * 16 + i * 4] = o;
  }
}

extern "C" void kernel_launch(void* const* d_in, const int* in_sizes, int n_in,
                              void* d_out, int out_size, void* d_ws, size_t ws_size,
                              hipStream_t stream) {
  const float* x = (const float*)d_in[0];
  const float* in_proj_w = (const float*)d_in[1];
  const float* conv_w = (const float*)d_in[2];
  const float* conv_b = (const float*)d_in[3];
  const float* dt_bias = (const float*)d_in[4];
  const float* A_log = (const float*)d_in[5];
  const float* Dvec = (const float*)d_in[6];
  const float* norm_w = (const float*)d_in[7];
  const float* out_proj_w = (const float*)d_in[8];

  char* ws = (char*)d_ws;
  u16* xbf    = (u16*)(ws + 0);
  u16* winbf  = (u16*)(ws + 33554432);
  u16* xs     = (u16*)(ws + 0);
  u16* yfbf   = (u16*)(ws + 0);
  u16* zY     = (u16*)(ws + 67895296);
  u16* xe     = (u16*)(ws + 135004160);
  u16* statesb= (u16*)(ws + 135004160);
  u16* woutbf = (u16*)(ws + 135004160);
  float* bce  = (float*)(ws + 202113024);
  float* dtb  = (float*)(ws + 206307328);
  float* Acs  = (float*)(ws + 208404480);
  float* Bfb  = (float*)(ws + 210501632);
  float* Cfb  = (float*)(ws + 212598784);
  float* cbt  = (float*)(ws + 214695936);

  cvt_kernel<<<16384, 256, 0, stream>>>(x, xbf, 4194304);
  cvt_kernel<<<16768, 256, 0, stream>>>(in_proj_w, winbf, 4292608);

  gemm_bt<1><<<dim3(64, 33), 512, 0, stream>>>(xbf, winbf, MROWS, DINPROJ, DMODEL,
                                               nullptr, zY, xe, bce, dtb);

  dt_acs_kernel<<<128, 64, 0, stream>>>(dtb, dt_bias, A_log, Acs);

  conv_silu_kernel<<<dim3(3, 64, 2), 256, 0, stream>>>(xe, bce, conv_w, conv_b, xs, Bfb, Cfb);

  states_kernel<<<8192, 256, 0, stream>>>(xs, Bfb, Acs, dtb, statesb);
  scan_kernel<<<2048, 256, 0, stream>>>(statesb, Acs);
  cbt_kernel<<<128, 256, 0, stream>>>(Bfb, Cfb, cbt);
  y_kernel<<<8192, 256, 0, stream>>>(xs, cbt, Cfb, Acs, dtb, statesb, Dvec, zY);

  rms_kernel<<<8192, 256, 0, stream>>>(zY, norm_w, yfbf);

  cvt_kernel<<<8192, 256, 0, stream>>>(out_proj_w, woutbf, 2097152);
  gemm_bt<0><<<dim3(64, 8), 512, 0, stream>>>(yfbf, woutbf, MROWS, DMODEL, DINNER,
                                              (float*)d_out, nullptr, nullptr, nullptr, nullptr);
}

// Round 12
// 744.098 us; speedup vs baseline: 1.2763x; 1.0766x over previous
//
#include <hip/hip_runtime.h>

#define BATCH 2
#define SEQ 4096
#define DMODEL 2048
#define DINNER 4096
#define NHEADS 64
#define HEADDIM 64
#define DSTATE 64
#define CONVDIM 4224
#define DINPROJ 8384
#define NCHUNK 64
#define CHUNKL 64
#define MROWS (BATCH*SEQ)   // 8192

typedef __bf16 bf16_t;
typedef bf16_t bf16x8 __attribute__((ext_vector_type(8)));
typedef float f32x4 __attribute__((ext_vector_type(4)));
typedef unsigned short u16;
typedef u16 u16x8 __attribute__((ext_vector_type(8)));

__device__ __forceinline__ u16 f2bf(float f) {
  unsigned int u = __float_as_uint(f);
  u += 0x7fff + ((u >> 16) & 1);
  return (u16)(u >> 16);
}
__device__ __forceinline__ float bf2f(u16 s) {
  return __uint_as_float(((unsigned int)s) << 16);
}

__device__ __forceinline__ void async_load16(const void* g, void* l) {
  __builtin_amdgcn_global_load_lds(
      (const __attribute__((address_space(1))) void*)g,
      (__attribute__((address_space(3))) void*)l, 16, 0, 0);
}

// ---------------- f32 -> bf16 convert ----------------
__global__ __launch_bounds__(256) void cvt_kernel(const float* __restrict__ in,
                                                  u16* __restrict__ out, int n4) {
  int i = blockIdx.x * 256 + threadIdx.x;
  if (i >= n4) return;
  float4 v = *(const float4*)(in + (size_t)i * 4);
  ushort4 o;
  o.x = f2bf(v.x); o.y = f2bf(v.y); o.z = f2bf(v.z); o.w = f2bf(v.w);
  *(ushort4*)(out + (size_t)i * 4) = o;
}

// ---------------- pipelined bf16 GEMM, B transposed (N x K)  [r7 structure] ----------
// 512 thr / 8 waves, tile 128x256xBK64, 3 LDS buffers, counted vmcnt(6),
// 1 barrier per K-tile, XOR-swizzled LDS (pre-swizzled global source).
// XCD swizzle: EPI==1 (K=2048): XCD owns 8 m-tiles (A-slice 4MB = L2).
//              EPI==0 (K=4096): XCD owns ONE 256-col n-panel (B-slice 2MB = L2),
//              walks all m-tiles (A served by L3; all XCDs walk m in lockstep).
// EPI 0: f32 out.  EPI 1: route z(bf16) / x-preact(bf16) / BC-preact(f32) / dt(f32)
template <int EPI>
__global__ __launch_bounds__(512, 2) void gemm_bt(const u16* __restrict__ A,
                                                  const u16* __restrict__ B,
                                                  int M, int N, int K,
                                                  float* __restrict__ outf,
                                                  u16* __restrict__ z_out,
                                                  u16* __restrict__ xe_out,
                                                  float* __restrict__ bce_out,
                                                  float* __restrict__ dt_out) {
  __shared__ char smem[147456];  // 3 x (A 16KB + B 32KB)
  const int tid = threadIdx.x;
  const int w = tid >> 6, lane = tid & 63;
  const int id = blockIdx.y * gridDim.x + blockIdx.x;
  int m0, n0;
  if (EPI == 0) {
    n0 = (id & 7) * 256;        // XCD owns one n-panel (2MB B-slice, L2-resident)
    m0 = (id >> 3) * 128;
  } else {
    const int xcd = id & 7;
    const int q = id >> 3;
    m0 = (xcd * 8 + (q & 7)) * 128;   // 4MB A-slice per XCD
    n0 = (q >> 3) * 256;
  }
  const int wr = (w >> 2) * 64, wc = (w & 3) * 64;
  const int fr = lane & 15, fq = lane >> 4;
  const int nkt = K >> 6;

  const u16* aptr[2];
  const u16* bptr[4];
#pragma unroll
  for (int p = 0; p < 2; ++p) {
    int d = p * 8192 + tid * 16;
    int row = d >> 7;
    int colb = (d & 127) ^ ((row & 7) << 4);
    aptr[p] = A + (size_t)(m0 + row) * K + (colb >> 1);
  }
#pragma unroll
  for (int p = 0; p < 4; ++p) {
    int d = p * 8192 + tid * 16;
    int row = d >> 7;
    int colb = (d & 127) ^ ((row & 7) << 4);
    int gn = n0 + row;
    if (gn > N - 1) gn = N - 1;
    bptr[p] = B + (size_t)gn * K + (colb >> 1);
  }

  auto stage_to = [&](int bi) {
    char* base = (char*)smem + bi * 49152;
#pragma unroll
    for (int p = 0; p < 2; ++p) {
      async_load16(aptr[p], base + p * 8192 + tid * 16);
      aptr[p] += 64;
    }
#pragma unroll
    for (int p = 0; p < 4; ++p) {
      async_load16(bptr[p], base + 16384 + p * 8192 + tid * 16);
      bptr[p] += 64;
    }
  };

  auto load_frags = [&](int bi, int ks, bf16x8* af, bf16x8* bf) {
    const char* base = (const char*)smem + bi * 49152;
#pragma unroll
    for (int i = 0; i < 4; ++i) {
      int rowa = wr + i * 16 + fr;
      af[i] = *(const bf16x8*)(base + ((rowa * 128 + ks * 64 + fq * 16) ^ ((fr & 7) << 4)));
      int rowb = wc + i * 16 + fr;
      bf[i] = *(const bf16x8*)(base + 16384 +
                               ((rowb * 128 + ks * 64 + fq * 16) ^ ((fr & 7) << 4)));
    }
  };

  f32x4 acc[4][4];
#pragma unroll
  for (int i = 0; i < 4; ++i)
#pragma unroll
    for (int j = 0; j < 4; ++j) acc[i][j] = (f32x4){0.f, 0.f, 0.f, 0.f};

  stage_to(0);
  stage_to(1);
  asm volatile("s_waitcnt vmcnt(6)" ::: "memory");
  __builtin_amdgcn_s_barrier();

  bf16x8 a0[4], b0[4], a1[4], b1[4];
  load_frags(0, 0, a0, b0);

  int cur = 0;
  for (int t = 0; t < nkt; ++t) {
    int nx = cur + 1; if (nx == 3) nx = 0;
    int st = nx + 1; if (st == 3) st = 0;
    load_frags(cur, 1, a1, b1);
    const bool do_stage = (t + 2 < nkt);
    if (do_stage) stage_to(st);
    __builtin_amdgcn_s_setprio(1);
#pragma unroll
    for (int i = 0; i < 4; ++i)
#pragma unroll
      for (int j = 0; j < 4; ++j)
        acc[i][j] = __builtin_amdgcn_mfma_f32_16x16x32_bf16(a0[i], b0[j], acc[i][j], 0, 0, 0);
    __builtin_amdgcn_s_setprio(0);
    if (do_stage) {
      asm volatile("s_waitcnt vmcnt(6)" ::: "memory");
    } else {
      asm volatile("s_waitcnt vmcnt(0)" ::: "memory");
    }
    __builtin_amdgcn_s_barrier();
    if (t + 1 < nkt) load_frags(nx, 0, a0, b0);
    __builtin_amdgcn_s_setprio(1);
#pragma unroll
    for (int i = 0; i < 4; ++i)
#pragma unroll
      for (int j = 0; j < 4; ++j)
        acc[i][j] = __builtin_amdgcn_mfma_f32_16x16x32_bf16(a1[i], b1[j], acc[i][j], 0, 0, 0);
    __builtin_amdgcn_s_setprio(0);
    cur = nx;
  }

#pragma unroll
  for (int i = 0; i < 4; ++i) {
#pragma unroll
    for (int j = 0; j < 4; ++j) {
#pragma unroll
      for (int rr2 = 0; rr2 < 4; ++rr2) {
        int row = m0 + wr + i * 16 + fq * 4 + rr2;
        int col = n0 + wc + j * 16 + fr;
        float v = acc[i][j][rr2];
        if (EPI == 0) {
          if (col < N) outf[(size_t)row * N + col] = v;
        } else {
          if (col < DINNER) {
            z_out[(size_t)row * DINNER + col] = f2bf(v);
          } else if (col < 2 * DINNER) {
            xe_out[(size_t)row * DINNER + (col - DINNER)] = f2bf(v);
          } else if (col < DINNER + CONVDIM) {
            bce_out[(size_t)row * 128 + (col - 2 * DINNER)] = v;
          } else if (col < DINPROJ) {
            dt_out[(size_t)row * NHEADS + (col - DINNER - CONVDIM)] = v;
          }
        }
      }
    }
  }
}

// ---------------- fused dt softplus (in place) + per-chunk cumsum of dA ----------------
__global__ __launch_bounds__(64) void dt_acs_kernel(float* __restrict__ dt,
                                                    const float* __restrict__ dt_bias,
                                                    const float* __restrict__ A_log,
                                                    float* __restrict__ Acs) {
  const int bid = blockIdx.x;  // b*64+c
  const int h = threadIdx.x;
  const float bias = dt_bias[h];
  const float nA = -expf(A_log[h]);
  float run = 0.f;
  float* acs_row = Acs + ((size_t)bid * 64 + h) * 64;
  for (int s = 0; s < 64; ++s) {
    size_t g = ((size_t)bid * 64 + s) * 64 + h;
    float xv = dt[g] + bias;
    float sp = (xv > 20.f) ? xv : log1pf(expf(xv));
    dt[g] = sp;
    run += nA * sp;
    acs_row[s] = run;
  }
}

// ---------------- causal depthwise conv4 + silu, register window along L ----------------
__global__ __launch_bounds__(256) void conv_silu_kernel(const u16* __restrict__ xe,
                                                        const float* __restrict__ bce,
                                                        const float* __restrict__ conv_w,
                                                        const float* __restrict__ conv_b,
                                                        u16* __restrict__ xs,
                                                        float* __restrict__ Bf,
                                                        float* __restrict__ Cf) {
  const int ch8 = blockIdx.x * 256 + threadIdx.x;
  if (ch8 >= CONVDIM / 8) return;  // 528
  const int b = blockIdx.z;
  const int l0 = blockIdx.y * 32;
  const int ch0 = ch8 * 8;
  const bool isx = ch0 < DINNER;
  float w[8][4], cb[8];
#pragma unroll
  for (int j = 0; j < 8; ++j) {
    cb[j] = conv_b[ch0 + j];
#pragma unroll
    for (int t = 0; t < 4; ++t) w[j][t] = conv_w[(ch0 + j) * 4 + t];
  }
  float win[3][8];
#pragma unroll
  for (int t = 0; t < 3; ++t) {
    int l = l0 - 3 + t;
    if (l < 0) {
#pragma unroll
      for (int j = 0; j < 8; ++j) win[t][j] = 0.f;
    } else if (isx) {
      const u16* p = &xe[((size_t)b * SEQ + l) * DINNER + ch0];
      ushort4 a = *(const ushort4*)p, bq = *(const ushort4*)(p + 4);
      win[t][0] = bf2f(a.x); win[t][1] = bf2f(a.y); win[t][2] = bf2f(a.z); win[t][3] = bf2f(a.w);
      win[t][4] = bf2f(bq.x); win[t][5] = bf2f(bq.y); win[t][6] = bf2f(bq.z); win[t][7] = bf2f(bq.w);
    } else {
      const float* p = &bce[((size_t)b * SEQ + l) * 128 + (ch0 - DINNER)];
      float4 a = *(const float4*)p, bq = *(const float4*)(p + 4);
      win[t][0] = a.x; win[t][1] = a.y; win[t][2] = a.z; win[t][3] = a.w;
      win[t][4] = bq.x; win[t][5] = bq.y; win[t][6] = bq.z; win[t][7] = bq.w;
    }
  }
  for (int li = 0; li < 32; ++li) {
    const int l = l0 + li;
    float cur[8];
    if (isx) {
      const u16* p = &xe[((size_t)b * SEQ + l) * DINNER + ch0];
      ushort4 a = *(const ushort4*)p, bq = *(const ushort4*)(p + 4);
      cur[0] = bf2f(a.x); cur[1] = bf2f(a.y); cur[2] = bf2f(a.z); cur[3] = bf2f(a.w);
      cur[4] = bf2f(bq.x); cur[5] = bf2f(bq.y); cur[6] = bf2f(bq.z); cur[7] = bf2f(bq.w);
    } else {
      const float* p = &bce[((size_t)b * SEQ + l) * 128 + (ch0 - DINNER)];
      float4 a = *(const float4*)p, bq = *(const float4*)(p + 4);
      cur[0] = a.x; cur[1] = a.y; cur[2] = a.z; cur[3] = a.w;
      cur[4] = bq.x; cur[5] = bq.y; cur[6] = bq.z; cur[7] = bq.w;
    }
    float o[8];
#pragma unroll
    for (int j = 0; j < 8; ++j) {
      float acc = cb[j] + w[j][0] * win[0][j] + w[j][1] * win[1][j] +
                  w[j][2] * win[2][j] + w[j][3] * cur[j];
      o[j] = acc / (1.f + expf(-acc));
    }
    if (isx) {
      const int h = ch0 >> 6, p0 = ch0 & 63;
      u16* dst = &xs[(((size_t)b * NHEADS + h) * SEQ + l) * 64 + p0];
      ushort4 s0, s1;
      s0.x = f2bf(o[0]); s0.y = f2bf(o[1]); s0.z = f2bf(o[2]); s0.w = f2bf(o[3]);
      s1.x = f2bf(o[4]); s1.y = f2bf(o[5]); s1.z = f2bf(o[6]); s1.w = f2bf(o[7]);
      *(ushort4*)dst = s0;
      *(ushort4*)(dst + 4) = s1;
    } else {
      const int c0 = ch0 - DINNER;
      float* dst = (c0 < DSTATE) ? &Bf[((size_t)b * SEQ + l) * 64 + c0]
                                 : &Cf[((size_t)b * SEQ + l) * 64 + (c0 - DSTATE)];
      float4 f0 = {o[0], o[1], o[2], o[3]}, f1 = {o[4], o[5], o[6], o[7]};
      *(float4*)dst = f0;
      *(float4*)(dst + 4) = f1;
    }
#pragma unroll
    for (int j = 0; j < 8; ++j) { win[0][j] = win[1][j]; win[1][j] = win[2][j]; win[2][j] = cur[j]; }
  }
}

// ---------------- MFMA states: states[p][n] = sum_s scale(s)*x[s,p]*B[s,n] ----------------
// 256 thr / 4 waves.  LDS: Axb [p][s] bf16 (transpose fill, x*scale), Bb [n][s] bf16
// (transpose fill).  Wave w owns p-strip [16w,16w+16): 8 MFMA.  Same tile code as y_kernel.
__global__ __launch_bounds__(256) void states_kernel(const u16* __restrict__ xs,
                                                     const float* __restrict__ Bf,
                                                     const float* __restrict__ Acs,
                                                     const float* __restrict__ dtp,
                                                     u16* __restrict__ states) {
  const int bid = blockIdx.x;  // (b*64+c)*64+h
  const int h = bid & 63, cc = (bid >> 6) & 63, b = bid >> 12;
  __shared__ char lds[16384 + 256];
  char* Axb = lds;
  char* Bb = lds + 8192;
  float* scale_s = (float*)(lds + 16384);
  const int tid = threadIdx.x;
  const float* acs = Acs + (size_t)bid * 64;
  const size_t blbase = (size_t)b * SEQ + cc * 64;
  if (tid < 64) {
    float alast = acs[63];
    scale_s[tid] = expf(alast - acs[tid]) * dtp[(blbase + tid) * 64 + h];
  }
  __syncthreads();
  const int r = tid >> 2, c0 = (tid & 3) * 16;
  {
    const float sc = scale_s[r];
    const u16* src = &xs[(((size_t)b * NHEADS + h) * SEQ + cc * 64 + r) * 64 + c0];
    u16x8 x0 = *(const u16x8*)src, x1 = *(const u16x8*)(src + 8);
    const float* bsrc = &Bf[(blbase + r) * 64 + c0];
    float4 bv0 = *(const float4*)bsrc, bv1 = *(const float4*)(bsrc + 4);
    float4 bv2 = *(const float4*)(bsrc + 8), bv3 = *(const float4*)(bsrc + 12);
    float ba[16] = {bv0.x, bv0.y, bv0.z, bv0.w, bv1.x, bv1.y, bv1.z, bv1.w,
                    bv2.x, bv2.y, bv2.z, bv2.w, bv3.x, bv3.y, bv3.z, bv3.w};
#pragma unroll
    for (int k = 0; k < 16; ++k) {
      u16 xv = (k < 8) ? x0[k] : x1[k - 8];
      int p = c0 + k;
      *(u16*)(Axb + ((p * 128 + r * 2) ^ ((p & 7) << 4))) = f2bf(bf2f(xv) * sc);
      *(u16*)(Bb + ((p * 128 + r * 2) ^ ((p & 7) << 4))) = f2bf(ba[k]);
    }
  }
  __syncthreads();
  const int w = tid >> 6, lane = tid & 63;
  const int fr = lane & 15, fq = lane >> 4;
  const int pw = w * 16;
  auto ldf = [&](const char* base, int row, int ks) -> bf16x8 {
    return *(const bf16x8*)(base + ((row * 128 + ks * 64 + fq * 16) ^ ((row & 7) << 4)));
  };
  bf16x8 aA[2];
  aA[0] = ldf(Axb, pw + fr, 0);
  aA[1] = ldf(Axb, pw + fr, 1);
  f32x4 acc[4];
#pragma unroll
  for (int j = 0; j < 4; ++j) acc[j] = (f32x4){0.f, 0.f, 0.f, 0.f};
#pragma unroll
  for (int j = 0; j < 4; ++j)
#pragma unroll
    for (int ks = 0; ks < 2; ++ks)
      acc[j] = __builtin_amdgcn_mfma_f32_16x16x32_bf16(aA[ks], ldf(Bb, j * 16 + fr, ks), acc[j], 0, 0, 0);
  u16* so = states + (size_t)bid * 4096;
#pragma unroll
  for (int j = 0; j < 4; ++j)
#pragma unroll
    for (int reg = 0; reg < 4; ++reg)
      so[(pw + fq * 4 + reg) * 64 + j * 16 + fr] = f2bf(acc[j][reg]);
}

// ---------------- inter-chunk scan (in place, bf16 storage, f32 carry) ----------------
__global__ __launch_bounds__(256) void scan_kernel(u16* __restrict__ states,
                                                   const float* __restrict__ Acs) {
  int idx = blockIdx.x * 256 + threadIdx.x;  // 524288: (b,h,p,n)
  int n = idx & 63, p = (idx >> 6) & 63, h = (idx >> 12) & 63, b = idx >> 18;
  float prev = 0.f;
  for (int c = 0; c < 64; ++c) {
    size_t bid = (size_t)(b * 64 + c) * 64 + h;
    size_t off = bid * 4096 + p * 64 + n;
    float sv = bf2f(states[off]);
    float cd = expf(Acs[bid * 64 + 63]);
    states[off] = f2bf(prev);
    prev = cd * prev + sv;
  }
}

// ---------------- CB^T once per (b,c): head-independent (NGROUPS=1) ----------------
__global__ __launch_bounds__(256) void cbt_kernel(const float* __restrict__ Bf,
                                                  const float* __restrict__ Cf,
                                                  float* __restrict__ cbt) {
  const int bc = blockIdx.x;  // b*64+c
  __shared__ float Ct[64 * 65];
  __shared__ float Bt[64 * 65];
  const int tid = threadIdx.x;
  const size_t blbase = (size_t)(bc >> 6) * SEQ + (bc & 63) * 64;
  const int c4 = (tid & 15) * 4;
  for (int rr = tid >> 4; rr < 64; rr += 16) {
    float4 cv = *(const float4*)&Cf[(blbase + rr) * 64 + c4];
    float4 bv = *(const float4*)&Bf[(blbase + rr) * 64 + c4];
    Ct[rr * 65 + c4 + 0] = cv.x; Ct[rr * 65 + c4 + 1] = cv.y;
    Ct[rr * 65 + c4 + 2] = cv.z; Ct[rr * 65 + c4 + 3] = cv.w;
    Bt[rr * 65 + c4 + 0] = bv.x; Bt[rr * 65 + c4 + 1] = bv.y;
    Bt[rr * 65 + c4 + 2] = bv.z; Bt[rr * 65 + c4 + 3] = bv.w;
  }
  __syncthreads();
  const int l0 = (tid >> 4) * 4, s0 = (tid & 15) * 4;
  float a1[4][4] = {};
  for (int n = 0; n < 64; ++n) {
    float cv[4], bv[4];
#pragma unroll
    for (int i = 0; i < 4; ++i) { cv[i] = Ct[(l0 + i) * 65 + n]; bv[i] = Bt[(s0 + i) * 65 + n]; }
#pragma unroll
    for (int i = 0; i < 4; ++i)
#pragma unroll
      for (int j = 0; j < 4; ++j) a1[i][j] += cv[i] * bv[j];
  }
  float* dst = cbt + (size_t)bc * 4096;
#pragma unroll
  for (int i = 0; i < 4; ++i) {
    float4 o = {a1[i][0], a1[i][1], a1[i][2], a1[i][3]};
    *(float4*)&dst[(l0 + i) * 64 + s0] = o;
  }
}

// ---------------- MFMA y_kernel: Y = (L*CBt)@xdt + expA*(C@prev^T) + D*x, gated ----------------
__global__ __launch_bounds__(256) void y_kernel(const u16* __restrict__ xs,
                                                const float* __restrict__ cbt,
                                                const float* __restrict__ Cf,
                                                const float* __restrict__ Acs,
                                                const float* __restrict__ dtp,
                                                const u16* __restrict__ prev,
                                                const float* __restrict__ Dv,
                                                u16* __restrict__ zY) {
  const int bid = blockIdx.x;  // (b*64+c)*64+h
  const int h = bid & 63, cc = (bid >> 6) & 63, b = bid >> 12;
  const int bc = bid >> 6;
  __shared__ char lds[32768 + 256];
  char* Cb = lds;
  char* Pb = lds + 8192;
  char* Sb = lds + 16384;
  char* Xb = lds + 24576;
  float* acsl = (float*)(lds + 32768);
  const int tid = threadIdx.x;
  const size_t blbase = (size_t)b * SEQ + cc * 64;
  if (tid < 64) acsl[tid] = Acs[(size_t)bid * 64 + tid];

  const int r = tid >> 2, c0 = (tid & 3) * 16;
  {
    const float* src = &Cf[(blbase + r) * 64 + c0];
    float4 a = *(const float4*)src, bq = *(const float4*)(src + 4);
    float4 c2 = *(const float4*)(src + 8), d2 = *(const float4*)(src + 12);
    u16x8 v0 = {f2bf(a.x), f2bf(a.y), f2bf(a.z), f2bf(a.w),
                f2bf(bq.x), f2bf(bq.y), f2bf(bq.z), f2bf(bq.w)};
    u16x8 v1 = {f2bf(c2.x), f2bf(c2.y), f2bf(c2.z), f2bf(c2.w),
                f2bf(d2.x), f2bf(d2.y), f2bf(d2.z), f2bf(d2.w)};
    *(u16x8*)(Cb + ((r * 128 + c0 * 2) ^ ((r & 7) << 4))) = v0;
    *(u16x8*)(Cb + ((r * 128 + c0 * 2 + 16) ^ ((r & 7) << 4))) = v1;
  }
  {
    const u16* src = &prev[(size_t)bid * 4096 + r * 64 + c0];
    u16x8 v0 = *(const u16x8*)src, v1 = *(const u16x8*)(src + 8);
    *(u16x8*)(Pb + ((r * 128 + c0 * 2) ^ ((r & 7) << 4))) = v0;
    *(u16x8*)(Pb + ((r * 128 + c0 * 2 + 16) ^ ((r & 7) << 4))) = v1;
  }
  {
    float dtv = dtp[(blbase + r) * 64 + h];
    const u16* src = &xs[(((size_t)b * NHEADS + h) * SEQ + cc * 64 + r) * 64 + c0];
    u16x8 x0 = *(const u16x8*)src, x1 = *(const u16x8*)(src + 8);
#pragma unroll
    for (int k = 0; k < 16; ++k) {
      u16 xv = (k < 8) ? x0[k] : x1[k - 8];
      u16 o = f2bf(bf2f(xv) * dtv);
      int p = c0 + k;
      *(u16*)(Xb + ((p * 128 + r * 2) ^ ((p & 7) << 4))) = o;
    }
  }
  __syncthreads();
  {
    float al = acsl[r];
    const float* src = &cbt[(size_t)bc * 4096 + r * 64 + c0];
    u16 ov[16];
#pragma unroll
    for (int k = 0; k < 16; ++k) {
      int s = c0 + k;
      float v = (r >= s) ? src[k] * expf(al - acsl[s]) : 0.f;
      ov[k] = f2bf(v);
    }
    u16x8 v0 = {ov[0], ov[1], ov[2], ov[3], ov[4], ov[5], ov[6], ov[7]};
    u16x8 v1 = {ov[8], ov[9], ov[10], ov[11], ov[12], ov[13], ov[14], ov[15]};
    *(u16x8*)(Sb + ((r * 128 + c0 * 2) ^ ((r & 7) << 4))) = v0;
    *(u16x8*)(Sb + ((r * 128 + c0 * 2 + 16) ^ ((r & 7) << 4))) = v1;
  }
  __syncthreads();

  const int w = tid >> 6, lane = tid & 63;
  const int fr = lane & 15, fq = lane >> 4;
  const int lw = w * 16;
  auto ldf = [&](const char* base, int row, int ks) -> bf16x8 {
    return *(const bf16x8*)(base + ((row * 128 + ks * 64 + fq * 16) ^ ((row & 7) << 4)));
  };
  bf16x8 aS[2], aC[2];
#pragma unroll
  for (int ks = 0; ks < 2; ++ks) {
    aS[ks] = ldf(Sb, lw + fr, ks);
    aC[ks] = ldf(Cb, lw + fr, ks);
  }
  f32x4 ay[4], ao[4];
#pragma unroll
  for (int j = 0; j < 4; ++j) { ay[j] = (f32x4){0.f,0.f,0.f,0.f}; ao[j] = (f32x4){0.f,0.f,0.f,0.f}; }
#pragma unroll
  for (int j = 0; j < 4; ++j) {
#pragma unroll
    for (int ks = 0; ks < 2; ++ks) {
      bf16x8 bX = ldf(Xb, j * 16 + fr, ks);
      ay[j] = __builtin_amdgcn_mfma_f32_16x16x32_bf16(aS[ks], bX, ay[j], 0, 0, 0);
      bf16x8 bP = ldf(Pb, j * 16 + fr, ks);
      ao[j] = __builtin_amdgcn_mfma_f32_16x16x32_bf16(aC[ks], bP, ao[j], 0, 0, 0);
    }
  }
  const float Dh = Dv[h];
  float el[4];
#pragma unroll
  for (int reg = 0; reg < 4; ++reg) el[reg] = expf(acsl[lw + fq * 4 + reg]);
#pragma unroll
  for (int j = 0; j < 4; ++j) {
#pragma unroll
    for (int reg = 0; reg < 4; ++reg) {
      int l = lw + fq * 4 + reg, p = j * 16 + fr;
      float yv = ay[j][reg] + el[reg] * ao[j][reg] +
                 Dh * bf2f(xs[(((size_t)b * NHEADS + h) * SEQ + cc * 64 + l) * 64 + p]);
      size_t zoff = (blbase + l) * DINNER + h * 64 + p;
      float zv = bf2f(zY[zoff]);
      zY[zoff] = f2bf(yv * (zv / (1.f + expf(-zv))));
    }
  }
}

// ---------------- RMSNorm of gated Y -> bf16 ----------------
__global__ __launch_bounds__(256) void rms_kernel(const u16* __restrict__ Y,
                                                  const float* __restrict__ nw,
                                                  u16* __restrict__ yf) {
  const int row = blockIdx.x, tid = threadIdx.x;
  const u16* yrow = Y + (size_t)row * DINNER;
  float g[16];
  float ss = 0.f;
#pragma unroll
  for (int i = 0; i < 4; ++i) {
    ushort4 yv = *(const ushort4*)&yrow[tid * 16 + i * 4];
    float ya[4] = {bf2f(yv.x), bf2f(yv.y), bf2f(yv.z), bf2f(yv.w)};
#pragma unroll
    for (int j = 0; j < 4; ++j) {
      g[i * 4 + j] = ya[j];
      ss += ya[j] * ya[j];
    }
  }
#pragma unroll
  for (int off = 32; off > 0; off >>= 1) ss += __shfl_down(ss, off, 64);
  __shared__ float red[4];
  if ((tid & 63) == 0) red[tid >> 6] = ss;
  __syncthreads();
  float tot = red[0] + red[1] + red[2] + red[3];
  float sc = rsqrtf(tot * (1.f / (float)DINNER) + 1e-5f);
#pragma unroll
  for (int i = 0; i < 4; ++i) {
    float4 nv = *(const float4*)&nw[tid * 16 + i * 4];
    float na[4] = {nv.x, nv.y, nv.z, nv.w};
    ushort4 o;
    o.x = f2bf(g[i * 4 + 0] * sc * na[0]);
    o.y = f2bf(g[i * 4 + 1] * sc * na[1]);
    o.z = f2bf(g[i * 4 + 2] * sc * na[2]);
    o.w = f2bf(g[i * 4 + 3] * sc * na[3]);
    *(ushort4*)&yf[(size_t)row * DINNER + tid * 16 + i * 4] = o;
  }
}

extern "C" void kernel_launch(void* const* d_in, const int* in_sizes, int n_in,
                              void* d_out, int out_size, void* d_ws, size_t ws_size,
                              hipStream_t stream) {
  const float* x = (const float*)d_in[0];
  const float* in_proj_w = (const float*)d_in[1];
  const float* conv_w = (const float*)d_in[2];
  const float* conv_b = (const float*)d_in[3];
  const float* dt_bias = (const float*)d_in[4];
  const float* A_log = (const float*)d_in[5];
  const float* Dvec = (const float*)d_in[6];
  const float* norm_w = (const float*)d_in[7];
  const float* out_proj_w = (const float*)d_in[8];

  char* ws = (char*)d_ws;
  u16* xbf    = (u16*)(ws + 0);
  u16* winbf  = (u16*)(ws + 33554432);
  u16* xs     = (u16*)(ws + 0);
  u16* yfbf   = (u16*)(ws + 0);
  u16* zY     = (u16*)(ws + 67895296);
  u16* xe     = (u16*)(ws + 135004160);
  u16* statesb= (u16*)(ws + 135004160);
  u16* woutbf = (u16*)(ws + 135004160);
  float* bce  = (float*)(ws + 202113024);
  float* dtb  = (float*)(ws + 206307328);
  float* Acs  = (float*)(ws + 208404480);
  float* Bfb  = (float*)(ws + 210501632);
  float* Cfb  = (float*)(ws + 212598784);
  float* cbt  = (float*)(ws + 214695936);

  cvt_kernel<<<16384, 256, 0, stream>>>(x, xbf, 4194304);
  cvt_kernel<<<16768, 256, 0, stream>>>(in_proj_w, winbf, 4292608);

  gemm_bt<1><<<dim3(64, 33), 512, 0, stream>>>(xbf, winbf, MROWS, DINPROJ, DMODEL,
                                               nullptr, zY, xe, bce, dtb);

  dt_acs_kernel<<<128, 64, 0, stream>>>(dtb, dt_bias, A_log, Acs);

  conv_silu_kernel<<<dim3(3, 128, 2), 256, 0, stream>>>(xe, bce, conv_w, conv_b, xs, Bfb, Cfb);

  states_kernel<<<8192, 256, 0, stream>>>(xs, Bfb, Acs, dtb, statesb);
  scan_kernel<<<2048, 256, 0, stream>>>(statesb, Acs);
  cbt_kernel<<<128, 256, 0, stream>>>(Bfb, Cfb, cbt);
  y_kernel<<<8192, 256, 0, stream>>>(xs, cbt, Cfb, Acs, dtb, statesb, Dvec, zY);

  rms_kernel<<<8192, 256, 0, stream>>>(zY, norm_w, yfbf);

  cvt_kernel<<<8192, 256, 0, stream>>>(out_proj_w, woutbf, 2097152);
  gemm_bt<0><<<dim3(64, 8), 512, 0, stream>>>(yfbf, woutbf, MROWS, DMODEL, DINNER,
                                              (float*)d_out, nullptr, nullptr, nullptr, nullptr);
}

// Round 13
// 732.367 us; speedup vs baseline: 1.2967x; 1.0160x over previous
//
#include <hip/hip_runtime.h>

#define BATCH 2
#define SEQ 4096
#define DMODEL 2048
#define DINNER 4096
#define NHEADS 64
#define HEADDIM 64
#define DSTATE 64
#define CONVDIM 4224
#define DINPROJ 8384
#define NCHUNK 64
#define CHUNKL 64
#define MROWS (BATCH*SEQ)   // 8192

typedef __bf16 bf16_t;
typedef bf16_t bf16x8 __attribute__((ext_vector_type(8)));
typedef float f32x4 __attribute__((ext_vector_type(4)));
typedef unsigned short u16;
typedef u16 u16x8 __attribute__((ext_vector_type(8)));

__device__ __forceinline__ u16 f2bf(float f) {
  unsigned int u = __float_as_uint(f);
  u += 0x7fff + ((u >> 16) & 1);
  return (u16)(u >> 16);
}
__device__ __forceinline__ float bf2f(u16 s) {
  return __uint_as_float(((unsigned int)s) << 16);
}

__device__ __forceinline__ void async_load16(const void* g, void* l) {
  __builtin_amdgcn_global_load_lds(
      (const __attribute__((address_space(1))) void*)g,
      (__attribute__((address_space(3))) void*)l, 16, 0, 0);
}

// ---------------- f32 -> bf16 convert ----------------
__global__ __launch_bounds__(256) void cvt_kernel(const float* __restrict__ in,
                                                  u16* __restrict__ out, int n4) {
  int i = blockIdx.x * 256 + threadIdx.x;
  if (i >= n4) return;
  float4 v = *(const float4*)(in + (size_t)i * 4);
  ushort4 o;
  o.x = f2bf(v.x); o.y = f2bf(v.y); o.z = f2bf(v.z); o.w = f2bf(v.w);
  *(ushort4*)(out + (size_t)i * 4) = o;
}

// ---------------- f32 -> bf16 convert with per-k norm_w fold (wout is N x K, K=4096) ----
__global__ __launch_bounds__(256) void cvt_norm_kernel(const float* __restrict__ in,
                                                       const float* __restrict__ nw,
                                                       u16* __restrict__ out, int n4) {
  int i = blockIdx.x * 256 + threadIdx.x;
  if (i >= n4) return;
  int k = (i * 4) & (DINNER - 1);
  float4 v = *(const float4*)(in + (size_t)i * 4);
  float4 nv = *(const float4*)(nw + k);
  ushort4 o;
  o.x = f2bf(v.x * nv.x); o.y = f2bf(v.y * nv.y);
  o.z = f2bf(v.z * nv.z); o.w = f2bf(v.w * nv.w);
  *(ushort4*)(out + (size_t)i * 4) = o;
}

// ---------------- pipelined bf16 GEMM, B transposed (N x K)  [r7 structure] ----------
// 512 thr / 8 waves, tile 128x256xBK64, 3 LDS buffers, counted vmcnt(6),
// 1 barrier per K-tile, XOR-swizzled LDS (pre-swizzled global source).
// XCD swizzle: EPI==1 (K=2048): XCD owns 8 m-tiles (A-slice 4MB = L2).
//              EPI==0 (K=4096): XCD owns ONE 256-col n-panel (B-slice 2MB = L2).
// EPI 0: f32 out scaled by scrow[row].  EPI 1: route z/x-preact/BC-preact/dt.
template <int EPI>
__global__ __launch_bounds__(512, 2) void gemm_bt(const u16* __restrict__ A,
                                                  const u16* __restrict__ B,
                                                  int M, int N, int K,
                                                  float* __restrict__ outf,
                                                  const float* __restrict__ scrow,
                                                  u16* __restrict__ z_out,
                                                  u16* __restrict__ xe_out,
                                                  float* __restrict__ bce_out,
                                                  float* __restrict__ dt_out) {
  __shared__ char smem[147456];  // 3 x (A 16KB + B 32KB)
  const int tid = threadIdx.x;
  const int w = tid >> 6, lane = tid & 63;
  const int id = blockIdx.y * gridDim.x + blockIdx.x;
  int m0, n0;
  if (EPI == 0) {
    n0 = (id & 7) * 256;
    m0 = (id >> 3) * 128;
  } else {
    const int xcd = id & 7;
    const int q = id >> 3;
    m0 = (xcd * 8 + (q & 7)) * 128;
    n0 = (q >> 3) * 256;
  }
  const int wr = (w >> 2) * 64, wc = (w & 3) * 64;
  const int fr = lane & 15, fq = lane >> 4;
  const int nkt = K >> 6;

  const u16* aptr[2];
  const u16* bptr[4];
#pragma unroll
  for (int p = 0; p < 2; ++p) {
    int d = p * 8192 + tid * 16;
    int row = d >> 7;
    int colb = (d & 127) ^ ((row & 7) << 4);
    aptr[p] = A + (size_t)(m0 + row) * K + (colb >> 1);
  }
#pragma unroll
  for (int p = 0; p < 4; ++p) {
    int d = p * 8192 + tid * 16;
    int row = d >> 7;
    int colb = (d & 127) ^ ((row & 7) << 4);
    int gn = n0 + row;
    if (gn > N - 1) gn = N - 1;
    bptr[p] = B + (size_t)gn * K + (colb >> 1);
  }

  auto stage_to = [&](int bi) {
    char* base = (char*)smem + bi * 49152;
#pragma unroll
    for (int p = 0; p < 2; ++p) {
      async_load16(aptr[p], base + p * 8192 + tid * 16);
      aptr[p] += 64;
    }
#pragma unroll
    for (int p = 0; p < 4; ++p) {
      async_load16(bptr[p], base + 16384 + p * 8192 + tid * 16);
      bptr[p] += 64;
    }
  };

  auto load_frags = [&](int bi, int ks, bf16x8* af, bf16x8* bf) {
    const char* base = (const char*)smem + bi * 49152;
#pragma unroll
    for (int i = 0; i < 4; ++i) {
      int rowa = wr + i * 16 + fr;
      af[i] = *(const bf16x8*)(base + ((rowa * 128 + ks * 64 + fq * 16) ^ ((fr & 7) << 4)));
      int rowb = wc + i * 16 + fr;
      bf[i] = *(const bf16x8*)(base + 16384 +
                               ((rowb * 128 + ks * 64 + fq * 16) ^ ((fr & 7) << 4)));
    }
  };

  f32x4 acc[4][4];
#pragma unroll
  for (int i = 0; i < 4; ++i)
#pragma unroll
    for (int j = 0; j < 4; ++j) acc[i][j] = (f32x4){0.f, 0.f, 0.f, 0.f};

  stage_to(0);
  stage_to(1);
  asm volatile("s_waitcnt vmcnt(6)" ::: "memory");
  __builtin_amdgcn_s_barrier();

  bf16x8 a0[4], b0[4], a1[4], b1[4];
  load_frags(0, 0, a0, b0);

  int cur = 0;
  for (int t = 0; t < nkt; ++t) {
    int nx = cur + 1; if (nx == 3) nx = 0;
    int st = nx + 1; if (st == 3) st = 0;
    load_frags(cur, 1, a1, b1);
    const bool do_stage = (t + 2 < nkt);
    if (do_stage) stage_to(st);
    __builtin_amdgcn_s_setprio(1);
#pragma unroll
    for (int i = 0; i < 4; ++i)
#pragma unroll
      for (int j = 0; j < 4; ++j)
        acc[i][j] = __builtin_amdgcn_mfma_f32_16x16x32_bf16(a0[i], b0[j], acc[i][j], 0, 0, 0);
    __builtin_amdgcn_s_setprio(0);
    if (do_stage) {
      asm volatile("s_waitcnt vmcnt(6)" ::: "memory");
    } else {
      asm volatile("s_waitcnt vmcnt(0)" ::: "memory");
    }
    __builtin_amdgcn_s_barrier();
    if (t + 1 < nkt) load_frags(nx, 0, a0, b0);
    __builtin_amdgcn_s_setprio(1);
#pragma unroll
    for (int i = 0; i < 4; ++i)
#pragma unroll
      for (int j = 0; j < 4; ++j)
        acc[i][j] = __builtin_amdgcn_mfma_f32_16x16x32_bf16(a1[i], b1[j], acc[i][j], 0, 0, 0);
    __builtin_amdgcn_s_setprio(0);
    cur = nx;
  }

#pragma unroll
  for (int i = 0; i < 4; ++i) {
#pragma unroll
    for (int j = 0; j < 4; ++j) {
#pragma unroll
      for (int rr2 = 0; rr2 < 4; ++rr2) {
        int row = m0 + wr + i * 16 + fq * 4 + rr2;
        int col = n0 + wc + j * 16 + fr;
        float v = acc[i][j][rr2];
        if (EPI == 0) {
          if (col < N) outf[(size_t)row * N + col] = v * scrow[row];
        } else {
          if (col < DINNER) {
            z_out[(size_t)row * DINNER + col] = f2bf(v);
          } else if (col < 2 * DINNER) {
            xe_out[(size_t)row * DINNER + (col - DINNER)] = f2bf(v);
          } else if (col < DINNER + CONVDIM) {
            bce_out[(size_t)row * 128 + (col - 2 * DINNER)] = v;
          } else if (col < DINPROJ) {
            dt_out[(size_t)row * NHEADS + (col - DINNER - CONVDIM)] = v;
          }
        }
      }
    }
  }
}

// ---------------- fused dt softplus (in place) + per-chunk cumsum of dA ----------------
__global__ __launch_bounds__(64) void dt_acs_kernel(float* __restrict__ dt,
                                                    const float* __restrict__ dt_bias,
                                                    const float* __restrict__ A_log,
                                                    float* __restrict__ Acs) {
  const int bid = blockIdx.x;  // b*64+c
  const int h = threadIdx.x;
  const float bias = dt_bias[h];
  const float nA = -expf(A_log[h]);
  float run = 0.f;
  float* acs_row = Acs + ((size_t)bid * 64 + h) * 64;
  for (int s = 0; s < 64; ++s) {
    size_t g = ((size_t)bid * 64 + s) * 64 + h;
    float xv = dt[g] + bias;
    float sp = (xv > 20.f) ? xv : log1pf(expf(xv));
    dt[g] = sp;
    run += nA * sp;
    acs_row[s] = run;
  }
}

// ---------------- causal depthwise conv4 + silu, register window along L ----------------
__global__ __launch_bounds__(256) void conv_silu_kernel(const u16* __restrict__ xe,
                                                        const float* __restrict__ bce,
                                                        const float* __restrict__ conv_w,
                                                        const float* __restrict__ conv_b,
                                                        u16* __restrict__ xs,
                                                        float* __restrict__ Bf,
                                                        float* __restrict__ Cf) {
  const int ch8 = blockIdx.x * 256 + threadIdx.x;
  if (ch8 >= CONVDIM / 8) return;  // 528
  const int b = blockIdx.z;
  const int l0 = blockIdx.y * 32;
  const int ch0 = ch8 * 8;
  const bool isx = ch0 < DINNER;
  float w[8][4], cb[8];
#pragma unroll
  for (int j = 0; j < 8; ++j) {
    cb[j] = conv_b[ch0 + j];
#pragma unroll
    for (int t = 0; t < 4; ++t) w[j][t] = conv_w[(ch0 + j) * 4 + t];
  }
  float win[3][8];
#pragma unroll
  for (int t = 0; t < 3; ++t) {
    int l = l0 - 3 + t;
    if (l < 0) {
#pragma unroll
      for (int j = 0; j < 8; ++j) win[t][j] = 0.f;
    } else if (isx) {
      const u16* p = &xe[((size_t)b * SEQ + l) * DINNER + ch0];
      ushort4 a = *(const ushort4*)p, bq = *(const ushort4*)(p + 4);
      win[t][0] = bf2f(a.x); win[t][1] = bf2f(a.y); win[t][2] = bf2f(a.z); win[t][3] = bf2f(a.w);
      win[t][4] = bf2f(bq.x); win[t][5] = bf2f(bq.y); win[t][6] = bf2f(bq.z); win[t][7] = bf2f(bq.w);
    } else {
      const float* p = &bce[((size_t)b * SEQ + l) * 128 + (ch0 - DINNER)];
      float4 a = *(const float4*)p, bq = *(const float4*)(p + 4);
      win[t][0] = a.x; win[t][1] = a.y; win[t][2] = a.z; win[t][3] = a.w;
      win[t][4] = bq.x; win[t][5] = bq.y; win[t][6] = bq.z; win[t][7] = bq.w;
    }
  }
  for (int li = 0; li < 32; ++li) {
    const int l = l0 + li;
    float cur[8];
    if (isx) {
      const u16* p = &xe[((size_t)b * SEQ + l) * DINNER + ch0];
      ushort4 a = *(const ushort4*)p, bq = *(const ushort4*)(p + 4);
      cur[0] = bf2f(a.x); cur[1] = bf2f(a.y); cur[2] = bf2f(a.z); cur[3] = bf2f(a.w);
      cur[4] = bf2f(bq.x); cur[5] = bf2f(bq.y); cur[6] = bf2f(bq.z); cur[7] = bf2f(bq.w);
    } else {
      const float* p = &bce[((size_t)b * SEQ + l) * 128 + (ch0 - DINNER)];
      float4 a = *(const float4*)p, bq = *(const float4*)(p + 4);
      cur[0] = a.x; cur[1] = a.y; cur[2] = a.z; cur[3] = a.w;
      cur[4] = bq.x; cur[5] = bq.y; cur[6] = bq.z; cur[7] = bq.w;
    }
    float o[8];
#pragma unroll
    for (int j = 0; j < 8; ++j) {
      float acc = cb[j] + w[j][0] * win[0][j] + w[j][1] * win[1][j] +
                  w[j][2] * win[2][j] + w[j][3] * cur[j];
      o[j] = acc / (1.f + expf(-acc));
    }
    if (isx) {
      const int h = ch0 >> 6, p0 = ch0 & 63;
      u16* dst = &xs[(((size_t)b * NHEADS + h) * SEQ + l) * 64 + p0];
      ushort4 s0, s1;
      s0.x = f2bf(o[0]); s0.y = f2bf(o[1]); s0.z = f2bf(o[2]); s0.w = f2bf(o[3]);
      s1.x = f2bf(o[4]); s1.y = f2bf(o[5]); s1.z = f2bf(o[6]); s1.w = f2bf(o[7]);
      *(ushort4*)dst = s0;
      *(ushort4*)(dst + 4) = s1;
    } else {
      const int c0 = ch0 - DINNER;
      float* dst = (c0 < DSTATE) ? &Bf[((size_t)b * SEQ + l) * 64 + c0]
                                 : &Cf[((size_t)b * SEQ + l) * 64 + (c0 - DSTATE)];
      float4 f0 = {o[0], o[1], o[2], o[3]}, f1 = {o[4], o[5], o[6], o[7]};
      *(float4*)dst = f0;
      *(float4*)(dst + 4) = f1;
    }
#pragma unroll
    for (int j = 0; j < 8; ++j) { win[0][j] = win[1][j]; win[1][j] = win[2][j]; win[2][j] = cur[j]; }
  }
}

// ---------------- MFMA states: states[p][n] = sum_s scale(s)*x[s,p]*B[s,n] ----------------
__global__ __launch_bounds__(256) void states_kernel(const u16* __restrict__ xs,
                                                     const float* __restrict__ Bf,
                                                     const float* __restrict__ Acs,
                                                     const float* __restrict__ dtp,
                                                     u16* __restrict__ states) {
  const int bid = blockIdx.x;  // (b*64+c)*64+h
  const int h = bid & 63, cc = (bid >> 6) & 63, b = bid >> 12;
  __shared__ char lds[16384 + 256];
  char* Axb = lds;
  char* Bb = lds + 8192;
  float* scale_s = (float*)(lds + 16384);
  const int tid = threadIdx.x;
  const float* acs = Acs + (size_t)bid * 64;
  const size_t blbase = (size_t)b * SEQ + cc * 64;
  if (tid < 64) {
    float alast = acs[63];
    scale_s[tid] = expf(alast - acs[tid]) * dtp[(blbase + tid) * 64 + h];
  }
  __syncthreads();
  const int r = tid >> 2, c0 = (tid & 3) * 16;
  {
    const float sc = scale_s[r];
    const u16* src = &xs[(((size_t)b * NHEADS + h) * SEQ + cc * 64 + r) * 64 + c0];
    u16x8 x0 = *(const u16x8*)src, x1 = *(const u16x8*)(src + 8);
    const float* bsrc = &Bf[(blbase + r) * 64 + c0];
    float4 bv0 = *(const float4*)bsrc, bv1 = *(const float4*)(bsrc + 4);
    float4 bv2 = *(const float4*)(bsrc + 8), bv3 = *(const float4*)(bsrc + 12);
    float ba[16] = {bv0.x, bv0.y, bv0.z, bv0.w, bv1.x, bv1.y, bv1.z, bv1.w,
                    bv2.x, bv2.y, bv2.z, bv2.w, bv3.x, bv3.y, bv3.z, bv3.w};
#pragma unroll
    for (int k = 0; k < 16; ++k) {
      u16 xv = (k < 8) ? x0[k] : x1[k - 8];
      int p = c0 + k;
      *(u16*)(Axb + ((p * 128 + r * 2) ^ ((p & 7) << 4))) = f2bf(bf2f(xv) * sc);
      *(u16*)(Bb + ((p * 128 + r * 2) ^ ((p & 7) << 4))) = f2bf(ba[k]);
    }
  }
  __syncthreads();
  const int w = tid >> 6, lane = tid & 63;
  const int fr = lane & 15, fq = lane >> 4;
  const int pw = w * 16;
  auto ldf = [&](const char* base, int row, int ks) -> bf16x8 {
    return *(const bf16x8*)(base + ((row * 128 + ks * 64 + fq * 16) ^ ((row & 7) << 4)));
  };
  bf16x8 aA[2];
  aA[0] = ldf(Axb, pw + fr, 0);
  aA[1] = ldf(Axb, pw + fr, 1);
  f32x4 acc[4];
#pragma unroll
  for (int j = 0; j < 4; ++j) acc[j] = (f32x4){0.f, 0.f, 0.f, 0.f};
#pragma unroll
  for (int j = 0; j < 4; ++j)
#pragma unroll
    for (int ks = 0; ks < 2; ++ks)
      acc[j] = __builtin_amdgcn_mfma_f32_16x16x32_bf16(aA[ks], ldf(Bb, j * 16 + fr, ks), acc[j], 0, 0, 0);
  u16* so = states + (size_t)bid * 4096;
#pragma unroll
  for (int j = 0; j < 4; ++j)
#pragma unroll
    for (int reg = 0; reg < 4; ++reg)
      so[(pw + fq * 4 + reg) * 64 + j * 16 + fr] = f2bf(acc[j][reg]);
}

// ---------------- inter-chunk scan (in place, bf16 storage, f32 carry) ----------------
__global__ __launch_bounds__(256) void scan_kernel(u16* __restrict__ states,
                                                   const float* __restrict__ Acs) {
  int idx = blockIdx.x * 256 + threadIdx.x;  // 524288: (b,h,p,n)
  int n = idx & 63, p = (idx >> 6) & 63, h = (idx >> 12) & 63, b = idx >> 18;
  float prev = 0.f;
  for (int c = 0; c < 64; ++c) {
    size_t bid = (size_t)(b * 64 + c) * 64 + h;
    size_t off = bid * 4096 + p * 64 + n;
    float sv = bf2f(states[off]);
    float cd = expf(Acs[bid * 64 + 63]);
    states[off] = f2bf(prev);
    prev = cd * prev + sv;
  }
}

// ---------------- CB^T once per (b,c): head-independent (NGROUPS=1) ----------------
__global__ __launch_bounds__(256) void cbt_kernel(const float* __restrict__ Bf,
                                                  const float* __restrict__ Cf,
                                                  float* __restrict__ cbt) {
  const int bc = blockIdx.x;  // b*64+c
  __shared__ float Ct[64 * 65];
  __shared__ float Bt[64 * 65];
  const int tid = threadIdx.x;
  const size_t blbase = (size_t)(bc >> 6) * SEQ + (bc & 63) * 64;
  const int c4 = (tid & 15) * 4;
  for (int rr = tid >> 4; rr < 64; rr += 16) {
    float4 cv = *(const float4*)&Cf[(blbase + rr) * 64 + c4];
    float4 bv = *(const float4*)&Bf[(blbase + rr) * 64 + c4];
    Ct[rr * 65 + c4 + 0] = cv.x; Ct[rr * 65 + c4 + 1] = cv.y;
    Ct[rr * 65 + c4 + 2] = cv.z; Ct[rr * 65 + c4 + 3] = cv.w;
    Bt[rr * 65 + c4 + 0] = bv.x; Bt[rr * 65 + c4 + 1] = bv.y;
    Bt[rr * 65 + c4 + 2] = bv.z; Bt[rr * 65 + c4 + 3] = bv.w;
  }
  __syncthreads();
  const int l0 = (tid >> 4) * 4, s0 = (tid & 15) * 4;
  float a1[4][4] = {};
  for (int n = 0; n < 64; ++n) {
    float cv[4], bv[4];
#pragma unroll
    for (int i = 0; i < 4; ++i) { cv[i] = Ct[(l0 + i) * 65 + n]; bv[i] = Bt[(s0 + i) * 65 + n]; }
#pragma unroll
    for (int i = 0; i < 4; ++i)
#pragma unroll
      for (int j = 0; j < 4; ++j) a1[i][j] += cv[i] * bv[j];
  }
  float* dst = cbt + (size_t)bc * 4096;
#pragma unroll
  for (int i = 0; i < 4; ++i) {
    float4 o = {a1[i][0], a1[i][1], a1[i][2], a1[i][3]};
    *(float4*)&dst[(l0 + i) * 64 + s0] = o;
  }
}

// ---------------- MFMA y_kernel: Y = (L*CBt)@xdt + expA*(C@prev^T) + D*x, gated,
// in place over z; also emits per-(b,c,h) row partial sum of g^2 for fused RMSNorm ----
__global__ __launch_bounds__(256) void y_kernel(const u16* __restrict__ xs,
                                                const float* __restrict__ cbt,
                                                const float* __restrict__ Cf,
                                                const float* __restrict__ Acs,
                                                const float* __restrict__ dtp,
                                                const u16* __restrict__ prev,
                                                const float* __restrict__ Dv,
                                                u16* __restrict__ zY,
                                                float* __restrict__ psum) {
  const int bid = blockIdx.x;  // (b*64+c)*64+h
  const int h = bid & 63, cc = (bid >> 6) & 63, b = bid >> 12;
  const int bc = bid >> 6;
  __shared__ char lds[32768 + 256];
  char* Cb = lds;
  char* Pb = lds + 8192;
  char* Sb = lds + 16384;
  char* Xb = lds + 24576;
  float* acsl = (float*)(lds + 32768);
  const int tid = threadIdx.x;
  const size_t blbase = (size_t)b * SEQ + cc * 64;
  if (tid < 64) acsl[tid] = Acs[(size_t)bid * 64 + tid];

  const int r = tid >> 2, c0 = (tid & 3) * 16;
  {
    const float* src = &Cf[(blbase + r) * 64 + c0];
    float4 a = *(const float4*)src, bq = *(const float4*)(src + 4);
    float4 c2 = *(const float4*)(src + 8), d2 = *(const float4*)(src + 12);
    u16x8 v0 = {f2bf(a.x), f2bf(a.y), f2bf(a.z), f2bf(a.w),
                f2bf(bq.x), f2bf(bq.y), f2bf(bq.z), f2bf(bq.w)};
    u16x8 v1 = {f2bf(c2.x), f2bf(c2.y), f2bf(c2.z), f2bf(c2.w),
                f2bf(d2.x), f2bf(d2.y), f2bf(d2.z), f2bf(d2.w)};
    *(u16x8*)(Cb + ((r * 128 + c0 * 2) ^ ((r & 7) << 4))) = v0;
    *(u16x8*)(Cb + ((r * 128 + c0 * 2 + 16) ^ ((r & 7) << 4))) = v1;
  }
  {
    const u16* src = &prev[(size_t)bid * 4096 + r * 64 + c0];
    u16x8 v0 = *(const u16x8*)src, v1 = *(const u16x8*)(src + 8);
    *(u16x8*)(Pb + ((r * 128 + c0 * 2) ^ ((r & 7) << 4))) = v0;
    *(u16x8*)(Pb + ((r * 128 + c0 * 2 + 16) ^ ((r & 7) << 4))) = v1;
  }
  {
    float dtv = dtp[(blbase + r) * 64 + h];
    const u16* src = &xs[(((size_t)b * NHEADS + h) * SEQ + cc * 64 + r) * 64 + c0];
    u16x8 x0 = *(const u16x8*)src, x1 = *(const u16x8*)(src + 8);
#pragma unroll
    for (int k = 0; k < 16; ++k) {
      u16 xv = (k < 8) ? x0[k] : x1[k - 8];
      u16 o = f2bf(bf2f(xv) * dtv);
      int p = c0 + k;
      *(u16*)(Xb + ((p * 128 + r * 2) ^ ((p & 7) << 4))) = o;
    }
  }
  __syncthreads();
  {
    float al = acsl[r];
    const float* src = &cbt[(size_t)bc * 4096 + r * 64 + c0];
    u16 ov[16];
#pragma unroll
    for (int k = 0; k < 16; ++k) {
      int s = c0 + k;
      float v = (r >= s) ? src[k] * expf(al - acsl[s]) : 0.f;
      ov[k] = f2bf(v);
    }
    u16x8 v0 = {ov[0], ov[1], ov[2], ov[3], ov[4], ov[5], ov[6], ov[7]};
    u16x8 v1 = {ov[8], ov[9], ov[10], ov[11], ov[12], ov[13], ov[14], ov[15]};
    *(u16x8*)(Sb + ((r * 128 + c0 * 2) ^ ((r & 7) << 4))) = v0;
    *(u16x8*)(Sb + ((r * 128 + c0 * 2 + 16) ^ ((r & 7) << 4))) = v1;
  }
  __syncthreads();

  const int w = tid >> 6, lane = tid & 63;
  const int fr = lane & 15, fq = lane >> 4;
  const int lw = w * 16;
  auto ldf = [&](const char* base, int row, int ks) -> bf16x8 {
    return *(const bf16x8*)(base + ((row * 128 + ks * 64 + fq * 16) ^ ((row & 7) << 4)));
  };
  bf16x8 aS[2], aC[2];
#pragma unroll
  for (int ks = 0; ks < 2; ++ks) {
    aS[ks] = ldf(Sb, lw + fr, ks);
    aC[ks] = ldf(Cb, lw + fr, ks);
  }
  f32x4 ay[4], ao[4];
#pragma unroll
  for (int j = 0; j < 4; ++j) { ay[j] = (f32x4){0.f,0.f,0.f,0.f}; ao[j] = (f32x4){0.f,0.f,0.f,0.f}; }
#pragma unroll
  for (int j = 0; j < 4; ++j) {
#pragma unroll
    for (int ks = 0; ks < 2; ++ks) {
      bf16x8 bX = ldf(Xb, j * 16 + fr, ks);
      ay[j] = __builtin_amdgcn_mfma_f32_16x16x32_bf16(aS[ks], bX, ay[j], 0, 0, 0);
      bf16x8 bP = ldf(Pb, j * 16 + fr, ks);
      ao[j] = __builtin_amdgcn_mfma_f32_16x16x32_bf16(aC[ks], bP, ao[j], 0, 0, 0);
    }
  }
  const float Dh = Dv[h];
  float el[4], rs[4] = {0.f, 0.f, 0.f, 0.f};
#pragma unroll
  for (int reg = 0; reg < 4; ++reg) el[reg] = expf(acsl[lw + fq * 4 + reg]);
#pragma unroll
  for (int j = 0; j < 4; ++j) {
#pragma unroll
    for (int reg = 0; reg < 4; ++reg) {
      int l = lw + fq * 4 + reg, p = j * 16 + fr;
      float yv = ay[j][reg] + el[reg] * ao[j][reg] +
                 Dh * bf2f(xs[(((size_t)b * NHEADS + h) * SEQ + cc * 64 + l) * 64 + p]);
      size_t zoff = (blbase + l) * DINNER + h * 64 + p;
      float zv = bf2f(zY[zoff]);
      float g = yv * (zv / (1.f + expf(-zv)));
      zY[zoff] = f2bf(g);
      rs[reg] += g * g;
    }
  }
  // reduce rs over the 16 fr-lanes of each fq group, write per-row partials
#pragma unroll
  for (int reg = 0; reg < 4; ++reg) {
#pragma unroll
    for (int off = 1; off < 16; off <<= 1) rs[reg] += __shfl_xor(rs[reg], off, 64);
  }
  if (fr == 0) {
#pragma unroll
    for (int reg = 0; reg < 4; ++reg)
      psum[(size_t)bid * 64 + lw + fq * 4 + reg] = rs[reg];
  }
}

// ---------------- finish RMS: sc[row] = rsqrt(mean_k g^2 + eps) ----------------
__global__ __launch_bounds__(256) void rms_finish_kernel(const float* __restrict__ psum,
                                                         float* __restrict__ scrow) {
  int row = blockIdx.x * 256 + threadIdx.x;  // 8192
  int b = row >> 12, cc = (row >> 6) & 63, l = row & 63;
  const float* p = psum + (((size_t)(b * 64 + cc)) * 64) * 64 + l;
  float s = 0.f;
#pragma unroll 8
  for (int h = 0; h < 64; ++h) s += p[h * 64];
  scrow[row] = rsqrtf(s * (1.f / (float)DINNER) + 1e-5f);
}

extern "C" void kernel_launch(void* const* d_in, const int* in_sizes, int n_in,
                              void* d_out, int out_size, void* d_ws, size_t ws_size,
                              hipStream_t stream) {
  const float* x = (const float*)d_in[0];
  const float* in_proj_w = (const float*)d_in[1];
  const float* conv_w = (const float*)d_in[2];
  const float* conv_b = (const float*)d_in[3];
  const float* dt_bias = (const float*)d_in[4];
  const float* A_log = (const float*)d_in[5];
  const float* Dvec = (const float*)d_in[6];
  const float* norm_w = (const float*)d_in[7];
  const float* out_proj_w = (const float*)d_in[8];

  char* ws = (char*)d_ws;
  u16* xbf    = (u16*)(ws + 0);
  u16* winbf  = (u16*)(ws + 33554432);
  u16* xs     = (u16*)(ws + 0);
  u16* zY     = (u16*)(ws + 67895296);
  u16* xe     = (u16*)(ws + 135004160);
  u16* statesb= (u16*)(ws + 135004160);
  u16* woutbf = (u16*)(ws + 135004160);
  float* bce  = (float*)(ws + 202113024);   // dead after conv; reused below
  float* psum = (float*)(ws + 202113024);   // 2MB (reuses bce region)
  float* scrow= (float*)(ws + 204210176);   // 32KB
  float* dtb  = (float*)(ws + 206307328);
  float* Acs  = (float*)(ws + 208404480);
  float* Bfb  = (float*)(ws + 210501632);
  float* Cfb  = (float*)(ws + 212598784);
  float* cbt  = (float*)(ws + 214695936);

  cvt_kernel<<<16384, 256, 0, stream>>>(x, xbf, 4194304);
  cvt_kernel<<<16768, 256, 0, stream>>>(in_proj_w, winbf, 4292608);

  gemm_bt<1><<<dim3(64, 33), 512, 0, stream>>>(xbf, winbf, MROWS, DINPROJ, DMODEL,
                                               nullptr, nullptr, zY, xe, bce, dtb);

  dt_acs_kernel<<<128, 64, 0, stream>>>(dtb, dt_bias, A_log, Acs);

  conv_silu_kernel<<<dim3(3, 128, 2), 256, 0, stream>>>(xe, bce, conv_w, conv_b, xs, Bfb, Cfb);

  states_kernel<<<8192, 256, 0, stream>>>(xs, Bfb, Acs, dtb, statesb);
  scan_kernel<<<2048, 256, 0, stream>>>(statesb, Acs);
  cbt_kernel<<<128, 256, 0, stream>>>(Bfb, Cfb, cbt);
  y_kernel<<<8192, 256, 0, stream>>>(xs, cbt, Cfb, Acs, dtb, statesb, Dvec, zY, psum);

  rms_finish_kernel<<<32, 256, 0, stream>>>(psum, scrow);

  cvt_norm_kernel<<<8192, 256, 0, stream>>>(out_proj_w, norm_w, woutbf, 2097152);
  gemm_bt<0><<<dim3(64, 8), 512, 0, stream>>>(zY, woutbf, MROWS, DMODEL, DINNER,
                                              (float*)d_out, scrow, nullptr, nullptr, nullptr, nullptr);
}

// Round 14
// 728.255 us; speedup vs baseline: 1.3040x; 1.0056x over previous
//
#include <hip/hip_runtime.h>

#define BATCH 2
#define SEQ 4096
#define DMODEL 2048
#define DINNER 4096
#define NHEADS 64
#define HEADDIM 64
#define DSTATE 64
#define CONVDIM 4224
#define DINPROJ 8384
#define NCHUNK 64
#define CHUNKL 64
#define MROWS (BATCH*SEQ)   // 8192

typedef __bf16 bf16_t;
typedef bf16_t bf16x8 __attribute__((ext_vector_type(8)));
typedef float f32x4 __attribute__((ext_vector_type(4)));
typedef unsigned short u16;
typedef u16 u16x8 __attribute__((ext_vector_type(8)));

__device__ __forceinline__ u16 f2bf(float f) {
  unsigned int u = __float_as_uint(f);
  u += 0x7fff + ((u >> 16) & 1);
  return (u16)(u >> 16);
}
__device__ __forceinline__ float bf2f(u16 s) {
  return __uint_as_float(((unsigned int)s) << 16);
}

__device__ __forceinline__ void async_load16(const void* g, void* l) {
  __builtin_amdgcn_global_load_lds(
      (const __attribute__((address_space(1))) void*)g,
      (__attribute__((address_space(3))) void*)l, 16, 0, 0);
}

// ---------------- fused f32->bf16 converts: x | in_proj_w | out_proj_w*norm_w ----------
#define NX4 4194304
#define NW14 4292608
#define NW24 2097152
__global__ __launch_bounds__(256) void cvt_all_kernel(const float* __restrict__ x,
                                                      const float* __restrict__ w1,
                                                      const float* __restrict__ w2,
                                                      const float* __restrict__ nw,
                                                      u16* __restrict__ xbf,
                                                      u16* __restrict__ w1bf,
                                                      u16* __restrict__ w2bf) {
  int i = blockIdx.x * 256 + threadIdx.x;
  if (i < NX4) {
    float4 v = *(const float4*)(x + (size_t)i * 4);
    ushort4 o;
    o.x = f2bf(v.x); o.y = f2bf(v.y); o.z = f2bf(v.z); o.w = f2bf(v.w);
    *(ushort4*)(xbf + (size_t)i * 4) = o;
  } else if (i < NX4 + NW14) {
    int j = i - NX4;
    float4 v = *(const float4*)(w1 + (size_t)j * 4);
    ushort4 o;
    o.x = f2bf(v.x); o.y = f2bf(v.y); o.z = f2bf(v.z); o.w = f2bf(v.w);
    *(ushort4*)(w1bf + (size_t)j * 4) = o;
  } else if (i < NX4 + NW14 + NW24) {
    int j = i - NX4 - NW14;
    int k = (j * 4) & (DINNER - 1);
    float4 v = *(const float4*)(w2 + (size_t)j * 4);
    float4 nv = *(const float4*)(nw + k);
    ushort4 o;
    o.x = f2bf(v.x * nv.x); o.y = f2bf(v.y * nv.y);
    o.z = f2bf(v.z * nv.z); o.w = f2bf(v.w * nv.w);
    *(ushort4*)(w2bf + (size_t)j * 4) = o;
  }
}

// ---------------- pipelined bf16 GEMM, B transposed (N x K)  [r7 structure] ----------
// 512 thr / 8 waves, tile 128x256xBK64, 3 LDS buffers, counted vmcnt(6),
// 1 barrier per K-tile, XOR-swizzled LDS (pre-swizzled global source).
// XCD swizzle: EPI==1 (K=2048): XCD owns 8 m-tiles (A-slice 4MB = L2).
//              EPI==0 (K=4096): XCD owns ONE 256-col n-panel (B-slice 2MB = L2).
// EPI 0: f32 out scaled by scrow[row].  EPI 1: route z/x-preact/BC-preact/dt.
template <int EPI>
__global__ __launch_bounds__(512, 2) void gemm_bt(const u16* __restrict__ A,
                                                  const u16* __restrict__ B,
                                                  int M, int N, int K,
                                                  float* __restrict__ outf,
                                                  const float* __restrict__ scrow,
                                                  u16* __restrict__ z_out,
                                                  u16* __restrict__ xe_out,
                                                  float* __restrict__ bce_out,
                                                  float* __restrict__ dt_out) {
  __shared__ char smem[147456];  // 3 x (A 16KB + B 32KB)
  const int tid = threadIdx.x;
  const int w = tid >> 6, lane = tid & 63;
  const int id = blockIdx.y * gridDim.x + blockIdx.x;
  int m0, n0;
  if (EPI == 0) {
    n0 = (id & 7) * 256;
    m0 = (id >> 3) * 128;
  } else {
    const int xcd = id & 7;
    const int q = id >> 3;
    m0 = (xcd * 8 + (q & 7)) * 128;
    n0 = (q >> 3) * 256;
  }
  const int wr = (w >> 2) * 64, wc = (w & 3) * 64;
  const int fr = lane & 15, fq = lane >> 4;
  const int nkt = K >> 6;

  const u16* aptr[2];
  const u16* bptr[4];
#pragma unroll
  for (int p = 0; p < 2; ++p) {
    int d = p * 8192 + tid * 16;
    int row = d >> 7;
    int colb = (d & 127) ^ ((row & 7) << 4);
    aptr[p] = A + (size_t)(m0 + row) * K + (colb >> 1);
  }
#pragma unroll
  for (int p = 0; p < 4; ++p) {
    int d = p * 8192 + tid * 16;
    int row = d >> 7;
    int colb = (d & 127) ^ ((row & 7) << 4);
    int gn = n0 + row;
    if (gn > N - 1) gn = N - 1;
    bptr[p] = B + (size_t)gn * K + (colb >> 1);
  }

  auto stage_to = [&](int bi) {
    char* base = (char*)smem + bi * 49152;
#pragma unroll
    for (int p = 0; p < 2; ++p) {
      async_load16(aptr[p], base + p * 8192 + tid * 16);
      aptr[p] += 64;
    }
#pragma unroll
    for (int p = 0; p < 4; ++p) {
      async_load16(bptr[p], base + 16384 + p * 8192 + tid * 16);
      bptr[p] += 64;
    }
  };

  auto load_frags = [&](int bi, int ks, bf16x8* af, bf16x8* bf) {
    const char* base = (const char*)smem + bi * 49152;
#pragma unroll
    for (int i = 0; i < 4; ++i) {
      int rowa = wr + i * 16 + fr;
      af[i] = *(const bf16x8*)(base + ((rowa * 128 + ks * 64 + fq * 16) ^ ((fr & 7) << 4)));
      int rowb = wc + i * 16 + fr;
      bf[i] = *(const bf16x8*)(base + 16384 +
                               ((rowb * 128 + ks * 64 + fq * 16) ^ ((fr & 7) << 4)));
    }
  };

  f32x4 acc[4][4];
#pragma unroll
  for (int i = 0; i < 4; ++i)
#pragma unroll
    for (int j = 0; j < 4; ++j) acc[i][j] = (f32x4){0.f, 0.f, 0.f, 0.f};

  stage_to(0);
  stage_to(1);
  asm volatile("s_waitcnt vmcnt(6)" ::: "memory");
  __builtin_amdgcn_s_barrier();

  bf16x8 a0[4], b0[4], a1[4], b1[4];
  load_frags(0, 0, a0, b0);

  int cur = 0;
  for (int t = 0; t < nkt; ++t) {
    int nx = cur + 1; if (nx == 3) nx = 0;
    int st = nx + 1; if (st == 3) st = 0;
    load_frags(cur, 1, a1, b1);
    const bool do_stage = (t + 2 < nkt);
    if (do_stage) stage_to(st);
    __builtin_amdgcn_s_setprio(1);
#pragma unroll
    for (int i = 0; i < 4; ++i)
#pragma unroll
      for (int j = 0; j < 4; ++j)
        acc[i][j] = __builtin_amdgcn_mfma_f32_16x16x32_bf16(a0[i], b0[j], acc[i][j], 0, 0, 0);
    __builtin_amdgcn_s_setprio(0);
    if (do_stage) {
      asm volatile("s_waitcnt vmcnt(6)" ::: "memory");
    } else {
      asm volatile("s_waitcnt vmcnt(0)" ::: "memory");
    }
    __builtin_amdgcn_s_barrier();
    if (t + 1 < nkt) load_frags(nx, 0, a0, b0);
    __builtin_amdgcn_s_setprio(1);
#pragma unroll
    for (int i = 0; i < 4; ++i)
#pragma unroll
      for (int j = 0; j < 4; ++j)
        acc[i][j] = __builtin_amdgcn_mfma_f32_16x16x32_bf16(a1[i], b1[j], acc[i][j], 0, 0, 0);
    __builtin_amdgcn_s_setprio(0);
    cur = nx;
  }

#pragma unroll
  for (int i = 0; i < 4; ++i) {
#pragma unroll
    for (int j = 0; j < 4; ++j) {
#pragma unroll
      for (int rr2 = 0; rr2 < 4; ++rr2) {
        int row = m0 + wr + i * 16 + fq * 4 + rr2;
        int col = n0 + wc + j * 16 + fr;
        float v = acc[i][j][rr2];
        if (EPI == 0) {
          if (col < N) outf[(size_t)row * N + col] = v * scrow[row];
        } else {
          if (col < DINNER) {
            z_out[(size_t)row * DINNER + col] = f2bf(v);
          } else if (col < 2 * DINNER) {
            xe_out[(size_t)row * DINNER + (col - DINNER)] = f2bf(v);
          } else if (col < DINNER + CONVDIM) {
            bce_out[(size_t)row * 128 + (col - 2 * DINNER)] = v;
          } else if (col < DINPROJ) {
            dt_out[(size_t)row * NHEADS + (col - DINNER - CONVDIM)] = v;
          }
        }
      }
    }
  }
}

// ---------------- fused dt softplus (in place) + per-chunk cumsum of dA ----------------
__global__ __launch_bounds__(64) void dt_acs_kernel(float* __restrict__ dt,
                                                    const float* __restrict__ dt_bias,
                                                    const float* __restrict__ A_log,
                                                    float* __restrict__ Acs) {
  const int bid = blockIdx.x;  // b*64+c
  const int h = threadIdx.x;
  const float bias = dt_bias[h];
  const float nA = -expf(A_log[h]);
  float run = 0.f;
  float* acs_row = Acs + ((size_t)bid * 64 + h) * 64;
  for (int s = 0; s < 64; ++s) {
    size_t g = ((size_t)bid * 64 + s) * 64 + h;
    float xv = dt[g] + bias;
    float sp = (xv > 20.f) ? xv : log1pf(expf(xv));
    dt[g] = sp;
    run += nA * sp;
    acs_row[s] = run;
  }
}

// ---------------- causal depthwise conv4 + silu, register window along L ----------------
__global__ __launch_bounds__(256) void conv_silu_kernel(const u16* __restrict__ xe,
                                                        const float* __restrict__ bce,
                                                        const float* __restrict__ conv_w,
                                                        const float* __restrict__ conv_b,
                                                        u16* __restrict__ xs,
                                                        float* __restrict__ Bf,
                                                        float* __restrict__ Cf) {
  const int ch8 = blockIdx.x * 256 + threadIdx.x;
  if (ch8 >= CONVDIM / 8) return;  // 528
  const int b = blockIdx.z;
  const int l0 = blockIdx.y * 32;
  const int ch0 = ch8 * 8;
  const bool isx = ch0 < DINNER;
  float w[8][4], cb[8];
#pragma unroll
  for (int j = 0; j < 8; ++j) {
    cb[j] = conv_b[ch0 + j];
#pragma unroll
    for (int t = 0; t < 4; ++t) w[j][t] = conv_w[(ch0 + j) * 4 + t];
  }
  float win[3][8];
#pragma unroll
  for (int t = 0; t < 3; ++t) {
    int l = l0 - 3 + t;
    if (l < 0) {
#pragma unroll
      for (int j = 0; j < 8; ++j) win[t][j] = 0.f;
    } else if (isx) {
      const u16* p = &xe[((size_t)b * SEQ + l) * DINNER + ch0];
      ushort4 a = *(const ushort4*)p, bq = *(const ushort4*)(p + 4);
      win[t][0] = bf2f(a.x); win[t][1] = bf2f(a.y); win[t][2] = bf2f(a.z); win[t][3] = bf2f(a.w);
      win[t][4] = bf2f(bq.x); win[t][5] = bf2f(bq.y); win[t][6] = bf2f(bq.z); win[t][7] = bf2f(bq.w);
    } else {
      const float* p = &bce[((size_t)b * SEQ + l) * 128 + (ch0 - DINNER)];
      float4 a = *(const float4*)p, bq = *(const float4*)(p + 4);
      win[t][0] = a.x; win[t][1] = a.y; win[t][2] = a.z; win[t][3] = a.w;
      win[t][4] = bq.x; win[t][5] = bq.y; win[t][6] = bq.z; win[t][7] = bq.w;
    }
  }
  for (int li = 0; li < 32; ++li) {
    const int l = l0 + li;
    float cur[8];
    if (isx) {
      const u16* p = &xe[((size_t)b * SEQ + l) * DINNER + ch0];
      ushort4 a = *(const ushort4*)p, bq = *(const ushort4*)(p + 4);
      cur[0] = bf2f(a.x); cur[1] = bf2f(a.y); cur[2] = bf2f(a.z); cur[3] = bf2f(a.w);
      cur[4] = bf2f(bq.x); cur[5] = bf2f(bq.y); cur[6] = bf2f(bq.z); cur[7] = bf2f(bq.w);
    } else {
      const float* p = &bce[((size_t)b * SEQ + l) * 128 + (ch0 - DINNER)];
      float4 a = *(const float4*)p, bq = *(const float4*)(p + 4);
      cur[0] = a.x; cur[1] = a.y; cur[2] = a.z; cur[3] = a.w;
      cur[4] = bq.x; cur[5] = bq.y; cur[6] = bq.z; cur[7] = bq.w;
    }
    float o[8];
#pragma unroll
    for (int j = 0; j < 8; ++j) {
      float acc = cb[j] + w[j][0] * win[0][j] + w[j][1] * win[1][j] +
                  w[j][2] * win[2][j] + w[j][3] * cur[j];
      o[j] = acc / (1.f + expf(-acc));
    }
    if (isx) {
      const int h = ch0 >> 6, p0 = ch0 & 63;
      u16* dst = &xs[(((size_t)b * NHEADS + h) * SEQ + l) * 64 + p0];
      ushort4 s0, s1;
      s0.x = f2bf(o[0]); s0.y = f2bf(o[1]); s0.z = f2bf(o[2]); s0.w = f2bf(o[3]);
      s1.x = f2bf(o[4]); s1.y = f2bf(o[5]); s1.z = f2bf(o[6]); s1.w = f2bf(o[7]);
      *(ushort4*)dst = s0;
      *(ushort4*)(dst + 4) = s1;
    } else {
      const int c0 = ch0 - DINNER;
      float* dst = (c0 < DSTATE) ? &Bf[((size_t)b * SEQ + l) * 64 + c0]
                                 : &Cf[((size_t)b * SEQ + l) * 64 + (c0 - DSTATE)];
      float4 f0 = {o[0], o[1], o[2], o[3]}, f1 = {o[4], o[5], o[6], o[7]};
      *(float4*)dst = f0;
      *(float4*)(dst + 4) = f1;
    }
#pragma unroll
    for (int j = 0; j < 8; ++j) { win[0][j] = win[1][j]; win[1][j] = win[2][j]; win[2][j] = cur[j]; }
  }
}

// ---------------- MFMA states: states[p][n] = sum_s scale(s)*x[s,p]*B[s,n] ----------------
__global__ __launch_bounds__(256) void states_kernel(const u16* __restrict__ xs,
                                                     const float* __restrict__ Bf,
                                                     const float* __restrict__ Acs,
                                                     const float* __restrict__ dtp,
                                                     u16* __restrict__ states) {
  const int bid = blockIdx.x;  // (b*64+c)*64+h
  const int h = bid & 63, cc = (bid >> 6) & 63, b = bid >> 12;
  __shared__ char lds[16384 + 256];
  char* Axb = lds;
  char* Bb = lds + 8192;
  float* scale_s = (float*)(lds + 16384);
  const int tid = threadIdx.x;
  const float* acs = Acs + (size_t)bid * 64;
  const size_t blbase = (size_t)b * SEQ + cc * 64;
  if (tid < 64) {
    float alast = acs[63];
    scale_s[tid] = expf(alast - acs[tid]) * dtp[(blbase + tid) * 64 + h];
  }
  __syncthreads();
  const int r = tid >> 2, c0 = (tid & 3) * 16;
  {
    const float sc = scale_s[r];
    const u16* src = &xs[(((size_t)b * NHEADS + h) * SEQ + cc * 64 + r) * 64 + c0];
    u16x8 x0 = *(const u16x8*)src, x1 = *(const u16x8*)(src + 8);
    const float* bsrc = &Bf[(blbase + r) * 64 + c0];
    float4 bv0 = *(const float4*)bsrc, bv1 = *(const float4*)(bsrc + 4);
    float4 bv2 = *(const float4*)(bsrc + 8), bv3 = *(const float4*)(bsrc + 12);
    float ba[16] = {bv0.x, bv0.y, bv0.z, bv0.w, bv1.x, bv1.y, bv1.z, bv1.w,
                    bv2.x, bv2.y, bv2.z, bv2.w, bv3.x, bv3.y, bv3.z, bv3.w};
#pragma unroll
    for (int k = 0; k < 16; ++k) {
      u16 xv = (k < 8) ? x0[k] : x1[k - 8];
      int p = c0 + k;
      *(u16*)(Axb + ((p * 128 + r * 2) ^ ((p & 7) << 4))) = f2bf(bf2f(xv) * sc);
      *(u16*)(Bb + ((p * 128 + r * 2) ^ ((p & 7) << 4))) = f2bf(ba[k]);
    }
  }
  __syncthreads();
  const int w = tid >> 6, lane = tid & 63;
  const int fr = lane & 15, fq = lane >> 4;
  const int pw = w * 16;
  auto ldf = [&](const char* base, int row, int ks) -> bf16x8 {
    return *(const bf16x8*)(base + ((row * 128 + ks * 64 + fq * 16) ^ ((row & 7) << 4)));
  };
  bf16x8 aA[2];
  aA[0] = ldf(Axb, pw + fr, 0);
  aA[1] = ldf(Axb, pw + fr, 1);
  f32x4 acc[4];
#pragma unroll
  for (int j = 0; j < 4; ++j) acc[j] = (f32x4){0.f, 0.f, 0.f, 0.f};
#pragma unroll
  for (int j = 0; j < 4; ++j)
#pragma unroll
    for (int ks = 0; ks < 2; ++ks)
      acc[j] = __builtin_amdgcn_mfma_f32_16x16x32_bf16(aA[ks], ldf(Bb, j * 16 + fr, ks), acc[j], 0, 0, 0);
  u16* so = states + (size_t)bid * 4096;
#pragma unroll
  for (int j = 0; j < 4; ++j)
#pragma unroll
    for (int reg = 0; reg < 4; ++reg)
      so[(pw + fq * 4 + reg) * 64 + j * 16 + fr] = f2bf(acc[j][reg]);
}

// ---------------- inter-chunk scan, coalesced ushort4 per thread ----------------
__global__ __launch_bounds__(256) void scan_kernel(u16* __restrict__ states,
                                                   const float* __restrict__ Acs) {
  int idx = blockIdx.x * 256 + threadIdx.x;  // 131072: (b,h,p,n4)
  int n4 = (idx & 15) * 4;
  int p = (idx >> 4) & 63;
  int h = (idx >> 10) & 63;
  int b = idx >> 16;
  float pr0 = 0.f, pr1 = 0.f, pr2 = 0.f, pr3 = 0.f;
  for (int c = 0; c < 64; ++c) {
    size_t bid = (size_t)(b * 64 + c) * 64 + h;
    u16* ptr = states + bid * 4096 + p * 64 + n4;
    ushort4 sv = *(ushort4*)ptr;
    float cd = expf(Acs[bid * 64 + 63]);
    ushort4 ov;
    ov.x = f2bf(pr0); ov.y = f2bf(pr1); ov.z = f2bf(pr2); ov.w = f2bf(pr3);
    *(ushort4*)ptr = ov;
    pr0 = cd * pr0 + bf2f(sv.x);
    pr1 = cd * pr1 + bf2f(sv.y);
    pr2 = cd * pr2 + bf2f(sv.z);
    pr3 = cd * pr3 + bf2f(sv.w);
  }
}

// ---------------- CB^T once per (b,c): head-independent (NGROUPS=1) ----------------
__global__ __launch_bounds__(256) void cbt_kernel(const float* __restrict__ Bf,
                                                  const float* __restrict__ Cf,
                                                  float* __restrict__ cbt) {
  const int bc = blockIdx.x;  // b*64+c
  __shared__ float Ct[64 * 65];
  __shared__ float Bt[64 * 65];
  const int tid = threadIdx.x;
  const size_t blbase = (size_t)(bc >> 6) * SEQ + (bc & 63) * 64;
  const int c4 = (tid & 15) * 4;
  for (int rr = tid >> 4; rr < 64; rr += 16) {
    float4 cv = *(const float4*)&Cf[(blbase + rr) * 64 + c4];
    float4 bv = *(const float4*)&Bf[(blbase + rr) * 64 + c4];
    Ct[rr * 65 + c4 + 0] = cv.x; Ct[rr * 65 + c4 + 1] = cv.y;
    Ct[rr * 65 + c4 + 2] = cv.z; Ct[rr * 65 + c4 + 3] = cv.w;
    Bt[rr * 65 + c4 + 0] = bv.x; Bt[rr * 65 + c4 + 1] = bv.y;
    Bt[rr * 65 + c4 + 2] = bv.z; Bt[rr * 65 + c4 + 3] = bv.w;
  }
  __syncthreads();
  const int l0 = (tid >> 4) * 4, s0 = (tid & 15) * 4;
  float a1[4][4] = {};
  for (int n = 0; n < 64; ++n) {
    float cv[4], bv[4];
#pragma unroll
    for (int i = 0; i < 4; ++i) { cv[i] = Ct[(l0 + i) * 65 + n]; bv[i] = Bt[(s0 + i) * 65 + n]; }
#pragma unroll
    for (int i = 0; i < 4; ++i)
#pragma unroll
      for (int j = 0; j < 4; ++j) a1[i][j] += cv[i] * bv[j];
  }
  float* dst = cbt + (size_t)bc * 4096;
#pragma unroll
  for (int i = 0; i < 4; ++i) {
    float4 o = {a1[i][0], a1[i][1], a1[i][2], a1[i][3]};
    *(float4*)&dst[(l0 + i) * 64 + s0] = o;
  }
}

// ---------------- MFMA y_kernel: Y = (L*CBt)@xdt + expA*(C@prev^T) + D*x, gated,
// in place over z; emits per-(b,c,h) row partial sum of g^2 for fused RMSNorm ----
__global__ __launch_bounds__(256) void y_kernel(const u16* __restrict__ xs,
                                                const float* __restrict__ cbt,
                                                const float* __restrict__ Cf,
                                                const float* __restrict__ Acs,
                                                const float* __restrict__ dtp,
                                                const u16* __restrict__ prev,
                                                const float* __restrict__ Dv,
                                                u16* __restrict__ zY,
                                                float* __restrict__ psum) {
  const int bid = blockIdx.x;  // (b*64+c)*64+h
  const int h = bid & 63, cc = (bid >> 6) & 63, b = bid >> 12;
  const int bc = bid >> 6;
  __shared__ char lds[32768 + 256];
  char* Cb = lds;
  char* Pb = lds + 8192;
  char* Sb = lds + 16384;
  char* Xb = lds + 24576;
  float* acsl = (float*)(lds + 32768);
  const int tid = threadIdx.x;
  const size_t blbase = (size_t)b * SEQ + cc * 64;
  if (tid < 64) acsl[tid] = Acs[(size_t)bid * 64 + tid];

  const int r = tid >> 2, c0 = (tid & 3) * 16;
  {
    const float* src = &Cf[(blbase + r) * 64 + c0];
    float4 a = *(const float4*)src, bq = *(const float4*)(src + 4);
    float4 c2 = *(const float4*)(src + 8), d2 = *(const float4*)(src + 12);
    u16x8 v0 = {f2bf(a.x), f2bf(a.y), f2bf(a.z), f2bf(a.w),
                f2bf(bq.x), f2bf(bq.y), f2bf(bq.z), f2bf(bq.w)};
    u16x8 v1 = {f2bf(c2.x), f2bf(c2.y), f2bf(c2.z), f2bf(c2.w),
                f2bf(d2.x), f2bf(d2.y), f2bf(d2.z), f2bf(d2.w)};
    *(u16x8*)(Cb + ((r * 128 + c0 * 2) ^ ((r & 7) << 4))) = v0;
    *(u16x8*)(Cb + ((r * 128 + c0 * 2 + 16) ^ ((r & 7) << 4))) = v1;
  }
  {
    const u16* src = &prev[(size_t)bid * 4096 + r * 64 + c0];
    u16x8 v0 = *(const u16x8*)src, v1 = *(const u16x8*)(src + 8);
    *(u16x8*)(Pb + ((r * 128 + c0 * 2) ^ ((r & 7) << 4))) = v0;
    *(u16x8*)(Pb + ((r * 128 + c0 * 2 + 16) ^ ((r & 7) << 4))) = v1;
  }
  {
    float dtv = dtp[(blbase + r) * 64 + h];
    const u16* src = &xs[(((size_t)b * NHEADS + h) * SEQ + cc * 64 + r) * 64 + c0];
    u16x8 x0 = *(const u16x8*)src, x1 = *(const u16x8*)(src + 8);
#pragma unroll
    for (int k = 0; k < 16; ++k) {
      u16 xv = (k < 8) ? x0[k] : x1[k - 8];
      u16 o = f2bf(bf2f(xv) * dtv);
      int p = c0 + k;
      *(u16*)(Xb + ((p * 128 + r * 2) ^ ((p & 7) << 4))) = o;
    }
  }
  __syncthreads();
  {
    float al = acsl[r];
    const float* src = &cbt[(size_t)bc * 4096 + r * 64 + c0];
    u16 ov[16];
#pragma unroll
    for (int k = 0; k < 16; ++k) {
      int s = c0 + k;
      float v = (r >= s) ? src[k] * expf(al - acsl[s]) : 0.f;
      ov[k] = f2bf(v);
    }
    u16x8 v0 = {ov[0], ov[1], ov[2], ov[3], ov[4], ov[5], ov[6], ov[7]};
    u16x8 v1 = {ov[8], ov[9], ov[10], ov[11], ov[12], ov[13], ov[14], ov[15]};
    *(u16x8*)(Sb + ((r * 128 + c0 * 2) ^ ((r & 7) << 4))) = v0;
    *(u16x8*)(Sb + ((r * 128 + c0 * 2 + 16) ^ ((r & 7) << 4))) = v1;
  }
  __syncthreads();

  const int w = tid >> 6, lane = tid & 63;
  const int fr = lane & 15, fq = lane >> 4;
  const int lw = w * 16;
  auto ldf = [&](const char* base, int row, int ks) -> bf16x8 {
    return *(const bf16x8*)(base + ((row * 128 + ks * 64 + fq * 16) ^ ((row & 7) << 4)));
  };
  bf16x8 aS[2], aC[2];
#pragma unroll
  for (int ks = 0; ks < 2; ++ks) {
    aS[ks] = ldf(Sb, lw + fr, ks);
    aC[ks] = ldf(Cb, lw + fr, ks);
  }
  f32x4 ay[4], ao[4];
#pragma unroll
  for (int j = 0; j < 4; ++j) { ay[j] = (f32x4){0.f,0.f,0.f,0.f}; ao[j] = (f32x4){0.f,0.f,0.f,0.f}; }
#pragma unroll
  for (int j = 0; j < 4; ++j) {
#pragma unroll
    for (int ks = 0; ks < 2; ++ks) {
      bf16x8 bX = ldf(Xb, j * 16 + fr, ks);
      ay[j] = __builtin_amdgcn_mfma_f32_16x16x32_bf16(aS[ks], bX, ay[j], 0, 0, 0);
      bf16x8 bP = ldf(Pb, j * 16 + fr, ks);
      ao[j] = __builtin_amdgcn_mfma_f32_16x16x32_bf16(aC[ks], bP, ao[j], 0, 0, 0);
    }
  }
  const float Dh = Dv[h];
  float el[4], rs[4] = {0.f, 0.f, 0.f, 0.f};
#pragma unroll
  for (int reg = 0; reg < 4; ++reg) el[reg] = expf(acsl[lw + fq * 4 + reg]);
#pragma unroll
  for (int j = 0; j < 4; ++j) {
#pragma unroll
    for (int reg = 0; reg < 4; ++reg) {
      int l = lw + fq * 4 + reg, p = j * 16 + fr;
      float yv = ay[j][reg] + el[reg] * ao[j][reg] +
                 Dh * bf2f(xs[(((size_t)b * NHEADS + h) * SEQ + cc * 64 + l) * 64 + p]);
      size_t zoff = (blbase + l) * DINNER + h * 64 + p;
      float zv = bf2f(zY[zoff]);
      float g = yv * (zv / (1.f + expf(-zv)));
      zY[zoff] = f2bf(g);
      rs[reg] += g * g;
    }
  }
#pragma unroll
  for (int reg = 0; reg < 4; ++reg) {
#pragma unroll
    for (int off = 1; off < 16; off <<= 1) rs[reg] += __shfl_xor(rs[reg], off, 64);
  }
  if (fr == 0) {
#pragma unroll
    for (int reg = 0; reg < 4; ++reg)
      psum[(size_t)bid * 64 + lw + fq * 4 + reg] = rs[reg];
  }
}

// ---------------- finish RMS: sc[row] = rsqrt(mean_k g^2 + eps) ----------------
__global__ __launch_bounds__(256) void rms_finish_kernel(const float* __restrict__ psum,
                                                         float* __restrict__ scrow) {
  int row = blockIdx.x * 256 + threadIdx.x;  // 8192
  int b = row >> 12, cc = (row >> 6) & 63, l = row & 63;
  const float* p = psum + (((size_t)(b * 64 + cc)) * 64) * 64 + l;
  float s = 0.f;
#pragma unroll 8
  for (int h = 0; h < 64; ++h) s += p[h * 64];
  scrow[row] = rsqrtf(s * (1.f / (float)DINNER) + 1e-5f);
}

extern "C" void kernel_launch(void* const* d_in, const int* in_sizes, int n_in,
                              void* d_out, int out_size, void* d_ws, size_t ws_size,
                              hipStream_t stream) {
  const float* x = (const float*)d_in[0];
  const float* in_proj_w = (const float*)d_in[1];
  const float* conv_w = (const float*)d_in[2];
  const float* conv_b = (const float*)d_in[3];
  const float* dt_bias = (const float*)d_in[4];
  const float* A_log = (const float*)d_in[5];
  const float* Dvec = (const float*)d_in[6];
  const float* norm_w = (const float*)d_in[7];
  const float* out_proj_w = (const float*)d_in[8];

  char* ws = (char*)d_ws;
  u16* xbf    = (u16*)(ws + 0);
  u16* winbf  = (u16*)(ws + 33554432);
  u16* xs     = (u16*)(ws + 0);
  u16* zY     = (u16*)(ws + 67895296);
  u16* xe     = (u16*)(ws + 135004160);
  u16* statesb= (u16*)(ws + 135004160);
  float* bce  = (float*)(ws + 202113024);   // dead after conv; reused as psum
  float* psum = (float*)(ws + 202113024);
  float* scrow= (float*)(ws + 204210176);
  float* dtb  = (float*)(ws + 206307328);
  float* Acs  = (float*)(ws + 208404480);
  float* Bfb  = (float*)(ws + 210501632);
  float* Cfb  = (float*)(ws + 212598784);
  float* cbt  = (float*)(ws + 214695936);
  u16* woutbf = (u16*)(ws + 216793088);     // own region (converted up front now)

  // fused converts (x, in_proj_w, out_proj_w*norm_w)
  cvt_all_kernel<<<41344, 256, 0, stream>>>(x, in_proj_w, out_proj_w, norm_w,
                                            xbf, winbf, woutbf);

  gemm_bt<1><<<dim3(64, 33), 512, 0, stream>>>(xbf, winbf, MROWS, DINPROJ, DMODEL,
                                               nullptr, nullptr, zY, xe, bce, dtb);

  dt_acs_kernel<<<128, 64, 0, stream>>>(dtb, dt_bias, A_log, Acs);

  conv_silu_kernel<<<dim3(3, 128, 2), 256, 0, stream>>>(xe, bce, conv_w, conv_b, xs, Bfb, Cfb);

  states_kernel<<<8192, 256, 0, stream>>>(xs, Bfb, Acs, dtb, statesb);
  scan_kernel<<<512, 256, 0, stream>>>(statesb, Acs);
  cbt_kernel<<<128, 256, 0, stream>>>(Bfb, Cfb, cbt);
  y_kernel<<<8192, 256, 0, stream>>>(xs, cbt, Cfb, Acs, dtb, statesb, Dvec, zY, psum);

  rms_finish_kernel<<<32, 256, 0, stream>>>(psum, scrow);

  gemm_bt<0><<<dim3(64, 8), 512, 0, stream>>>(zY, woutbf, MROWS, DMODEL, DINNER,
                                              (float*)d_out, scrow, nullptr, nullptr, nullptr, nullptr);
}